// Round 10
// baseline (290.362 us; speedup 1.0000x reference)
//
#include <hip/hip_runtime.h>
#include <stdint.h>

#define T_DIM 2048
#define D_DIM 1024
#define B_DIM 8
#define M_TOK (B_DIM * T_DIM)   // 16384 tokens
#define GAMMA_C 0.96875f

typedef float f32x4 __attribute__((ext_vector_type(4)));
typedef float f32x16 __attribute__((ext_vector_type(16)));
typedef float fl4 __attribute__((ext_vector_type(4)));
typedef __bf16 bf16x8 __attribute__((ext_vector_type(8)));
typedef unsigned short us8 __attribute__((ext_vector_type(8)));
typedef unsigned short us4 __attribute__((ext_vector_type(4)));

// ---------- bf16 helpers ----------
__device__ __forceinline__ unsigned short f32_bf16_rne(float f) {
  uint32_t u = __builtin_bit_cast(uint32_t, f);
  return (unsigned short)((u + 0x7FFFu + ((u >> 16) & 1u)) >> 16);
}
__device__ __forceinline__ float bf16_f32(unsigned short h) {
  uint32_t u = ((uint32_t)h) << 16;
  return __builtin_bit_cast(float, u);
}

// chunk swizzle for BK=32 tiles: spreads 32-row b128 column-slice reads
__device__ __forceinline__ int swz_row(int r) {
  return ((r >> 1) & 3) ^ ((r >> 3) & 3);
}

// ---------- global->LDS direct ----------
__device__ __forceinline__ void gload16(const void* g, void* l) {
  __builtin_amdgcn_global_load_lds(
      reinterpret_cast<const __attribute__((address_space(1))) uint32_t*>(
          reinterpret_cast<uintptr_t>(g)),
      reinterpret_cast<__attribute__((address_space(3))) uint32_t*>(
          reinterpret_cast<uintptr_t>(l)),
      16, 0, 0);
}

__device__ __forceinline__ bf16x8 ldfrag(const unsigned short* p) {
  us8 u = *reinterpret_cast<const us8*>(p);
  return __builtin_bit_cast(bf16x8, u);
}

#define VMW(n) asm volatile("s_waitcnt vmcnt(" #n ")" ::: "memory")
#define BAR    __builtin_amdgcn_s_barrier()

// ---------- split f32 -> (hi, lo) bf16, 16B stores ----------
__global__ __launch_bounds__(256) void k_split(const float* __restrict__ in, int n8,
                                               unsigned short* __restrict__ hi,
                                               unsigned short* __restrict__ lo) {
  int stride = gridDim.x * blockDim.x;
  for (int i = blockIdx.x * blockDim.x + threadIdx.x; i < n8; i += stride) {
    fl4 v0 = ((const fl4*)in)[i * 2];
    fl4 v1 = ((const fl4*)in)[i * 2 + 1];
    us8 h, l;
#pragma unroll
    for (int j = 0; j < 4; ++j) {
      unsigned short hb = f32_bf16_rne(v0[j]);
      h[j] = hb;
      l[j] = f32_bf16_rne(v0[j] - bf16_f32(hb));
      unsigned short hb1 = f32_bf16_rne(v1[j]);
      h[j + 4] = hb1;
      l[j + 4] = f32_bf16_rne(v1[j] - bf16_f32(hb1));
    }
    ((us8*)hi)[i] = h;
    ((us8*)lo)[i] = l;
  }
}

__global__ __launch_bounds__(256) void k_split_hi(const float* __restrict__ in, int n8,
                                                  unsigned short* __restrict__ hi) {
  int stride = gridDim.x * blockDim.x;
  for (int i = blockIdx.x * blockDim.x + threadIdx.x; i < n8; i += stride) {
    fl4 v0 = ((const fl4*)in)[i * 2];
    fl4 v1 = ((const fl4*)in)[i * 2 + 1];
    us8 h;
#pragma unroll
    for (int j = 0; j < 4; ++j) {
      h[j] = f32_bf16_rne(v0[j]);
      h[j + 4] = f32_bf16_rne(v1[j]);
    }
    ((us8*)hi)[i] = h;
  }
}

// ---------- transpose-split: out_t[d][e] = split(in[e][d]), 64x64 tiles ----------
__global__ __launch_bounds__(256) void k_split_T(const float* __restrict__ in,
                                                 unsigned short* __restrict__ th,
                                                 unsigned short* __restrict__ tl) {
  __shared__ float tile[64][69];
  int be = blockIdx.x >> 4, bd = blockIdx.x & 15;
  int e0 = be * 64, d0 = bd * 64;
  int r = threadIdx.x >> 4;
  int c = (threadIdx.x & 15) * 4;
#pragma unroll
  for (int it = 0; it < 4; ++it) {
    int rr = r + it * 16;
    fl4 v = *(const fl4*)(in + (size_t)(e0 + rr) * D_DIM + d0 + c);
#pragma unroll
    for (int j = 0; j < 4; ++j) tile[rr][c + j] = v[j];
  }
  __syncthreads();
#pragma unroll
  for (int it = 0; it < 4; ++it) {
    int dr = r + it * 16;
    us4 h, l;
#pragma unroll
    for (int j = 0; j < 4; ++j) {
      float f = tile[c + j][dr];
      h[j] = f32_bf16_rne(f);
      l[j] = f32_bf16_rne(f - bf16_f32(h[j]));
    }
    *(us4*)(th + (size_t)(d0 + dr) * D_DIM + e0 + c) = h;
    *(us4*)(tl + (size_t)(d0 + dr) * D_DIM + e0 + c) = l;
  }
}

// ---------- u[t] = GAMMA * rowsum(W_ih[t,:]) + b_ih[t] ----------
__global__ __launch_bounds__(256) void k_u(const float* __restrict__ Wih,
                                           const float* __restrict__ bih,
                                           float* __restrict__ u) {
  int wave = threadIdx.x >> 6, lane = threadIdx.x & 63;
  int t = blockIdx.x * 4 + wave;
  const fl4* row = (const fl4*)(Wih + (size_t)t * T_DIM);
  float s = 0.f;
#pragma unroll
  for (int i = 0; i < 8; ++i) {
    fl4 v = row[lane + i * 64];
    s += v[0] + v[1] + v[2] + v[3];
  }
#pragma unroll
  for (int m = 32; m >= 1; m >>= 1) s += __shfl_xor(s, m, 64);
  if (lane == 0) u[t] = GAMMA_C * s + bih[t];
}

// ---------- h_out[t] = tanh(u[t] + dot(Whh_bf16[t,:], h_prev) + bias_row[t]) ----------
__global__ __launch_bounds__(256) void k_step_bf(const unsigned short* __restrict__ Whh_b,
                                                 const float* __restrict__ hprev,
                                                 const float* __restrict__ u,
                                                 const float* __restrict__ biasrow,
                                                 float* __restrict__ hout) {
  int wave = threadIdx.x >> 6, lane = threadIdx.x & 63;
  int t = blockIdx.x * 4 + wave;
  const unsigned short* row = Whh_b + (size_t)t * T_DIM;
  float s = 0.f;
#pragma unroll
  for (int i = 0; i < 4; ++i) {
    us8 w = *(const us8*)(row + i * 512 + lane * 8);
    fl4 h0 = *(const fl4*)(hprev + i * 512 + lane * 8);
    fl4 h1 = *(const fl4*)(hprev + i * 512 + lane * 8 + 4);
    s += bf16_f32(w[0]) * h0[0] + bf16_f32(w[1]) * h0[1] +
         bf16_f32(w[2]) * h0[2] + bf16_f32(w[3]) * h0[3] +
         bf16_f32(w[4]) * h1[0] + bf16_f32(w[5]) * h1[1] +
         bf16_f32(w[6]) * h1[2] + bf16_f32(w[7]) * h1[3];
  }
#pragma unroll
  for (int m = 32; m >= 1; m >>= 1) s += __shfl_xor(s, m, 64);
  if (lane == 0) hout[t] = tanhf(u[t] + s + biasrow[t]);
}

// =====================================================================
// H[d'][d] = sum_e Wv[e,d'] * Wk[e,d], 3-term split, fp32 output.
// =====================================================================
__global__ __launch_bounds__(256) void k_ht(
    const unsigned short* __restrict__ ah, const unsigned short* __restrict__ al,
    const unsigned short* __restrict__ bh, const unsigned short* __restrict__ bl,
    float* __restrict__ Hf) {
  __shared__ unsigned short sAh[2][64 * 32], sAl[2][64 * 32];
  __shared__ unsigned short sBh[2][64 * 32], sBl[2][64 * 32];
  const int tid = threadIdx.x;
  const int wave = tid >> 6, lane = tid & 63;
  const int wm = wave >> 1, wn = wave & 1;
  const int m0 = (blockIdx.x >> 4) * 64, n0 = (blockIdx.x & 15) * 64;
  const int hi32 = lane >> 5;

  const int srow = tid >> 2;
  const int csrc = (tid & 3) ^ swz_row(srow);
  const size_t ga = (size_t)(m0 + srow) * D_DIM + csrc * 8;
  const size_t gb = (size_t)(n0 + srow) * D_DIM + csrc * 8;
  const int ldst = tid * 8;

  f32x16 acc = {};
  const int l31 = lane & 31;
  const int sw = swz_row(l31);
  const int ar = wm * 32 + l31;
  const int br = wn * 32 + l31;
  int aoff[2], boff[2];
#pragma unroll
  for (int kh = 0; kh < 2; ++kh) {
    aoff[kh] = ar * 32 + (((kh * 2 + hi32) ^ sw) * 8);
    boff[kh] = br * 32 + (((kh * 2 + hi32) ^ sw) * 8);
  }

  auto stage = [&](int t, int buf) {
    const size_t ko = (size_t)t * 32;
    gload16(ah + ga + ko, &sAh[buf][ldst]);
    gload16(al + ga + ko, &sAl[buf][ldst]);
    gload16(bh + gb + ko, &sBh[buf][ldst]);
    gload16(bl + gb + ko, &sBl[buf][ldst]);
  };

  stage(0, 0);
  stage(1, 1);
  for (int kt = 0; kt < 32; ++kt) {
    const int cur = kt & 1;
    if (kt < 31) { VMW(4); } else { VMW(0); }
    BAR;
#pragma unroll
    for (int kh = 0; kh < 2; ++kh) {
      bf16x8 fah = ldfrag(&sAh[cur][aoff[kh]]);
      bf16x8 fal = ldfrag(&sAl[cur][aoff[kh]]);
      bf16x8 fbh = ldfrag(&sBh[cur][boff[kh]]);
      bf16x8 fbl = ldfrag(&sBl[cur][boff[kh]]);
      acc = __builtin_amdgcn_mfma_f32_32x32x16_bf16(fah, fbh, acc, 0, 0, 0);
      acc = __builtin_amdgcn_mfma_f32_32x32x16_bf16(fah, fbl, acc, 0, 0, 0);
      acc = __builtin_amdgcn_mfma_f32_32x32x16_bf16(fal, fbh, acc, 0, 0, 0);
    }
    BAR;
    if (kt + 2 <= 31) stage(kt + 2, cur);
  }
#pragma unroll
  for (int r = 0; r < 16; ++r) {
    int row = m0 + wm * 32 + (r & 3) + 8 * (r >> 2) + 4 * hi32;
    int col = n0 + wn * 32 + l31;
    Hf[(size_t)row * D_DIM + col] = acc[r];
  }
}

// =====================================================================
// M'[d'][d] = H[d',d]+H[d,d'] (d>d'); H[d,d] (d==d'); 0 (d<d').
// =====================================================================
__global__ __launch_bounds__(256) void k_nprime(const float* __restrict__ Hf,
                                                unsigned short* __restrict__ mh,
                                                unsigned short* __restrict__ ml) {
  __shared__ float t2[64][65];
  const int ti = blockIdx.x >> 4;
  const int tj = blockIdx.x & 15;
  const int r0 = ti * 64, c0 = tj * 64;
  const int a = threadIdx.x >> 2;
  const int b4 = (threadIdx.x & 3) * 16;
  if (tj < ti) {
#pragma unroll
    for (int j = 0; j < 16; ++j) {
      size_t ad = (size_t)(r0 + a) * D_DIM + c0 + b4 + j;
      mh[ad] = 0;
      ml[ad] = 0;
    }
    return;
  }
#pragma unroll
  for (int j = 0; j < 16; j += 4) {
    fl4 v = *(const fl4*)(Hf + (size_t)(c0 + a) * D_DIM + r0 + b4 + j);
#pragma unroll
    for (int q = 0; q < 4; ++q) t2[a][b4 + j + q] = v[q];
  }
  __syncthreads();
#pragma unroll
  for (int j = 0; j < 16; ++j) {
    int dp = r0 + a;
    int dd = c0 + b4 + j;
    float v = 0.f;
    if (dd > dp)       v = Hf[(size_t)dp * D_DIM + dd] + t2[b4 + j][a];
    else if (dd == dp) v = Hf[(size_t)dp * D_DIM + dd];
    unsigned short hb = f32_bf16_rne(v);
    unsigned short lb = f32_bf16_rne(v - bf16_f32(hb));
    size_t ad = (size_t)dp * D_DIM + dd;
    mh[ad] = hb;
    ml[ad] = lb;
  }
}

// =====================================================================
// Y = x.M'^T fused bias — R6 schedule, BK=16 for occupancy:
//   LDS = 4 arrays x 2buf x 128x16x2B = 32 KB -> 4 blocks/CU (16 waves,
//   4/SIMD): 3 other independent blocks cover each block's barrier and
//   waitcnt stalls (R9 showed all pipes <25% busy at 2 blocks/CU).
//   4 waves (2x2), wave 64x64, MFMA 32x32x16, 3-term split, 12 MFMA/kt.
//   512 blocks paired {np, 7-np} -> exactly 72 kt each (kt0 = 8*nb, ke=64).
//   Per-kt frag working set: 8 frags (32 VGPR) + 64 acc -> no spill at
//   the 128-VGPR cap of launch_bounds(256,4).
//   BK=16 frag reads cover a full 32-row x 32B slab -> <=2-way bank
//   sharing (free, m136): no swizzle needed on this path.
// =====================================================================
__global__ __launch_bounds__(256, 4) void k_y_bias(
    const unsigned short* __restrict__ xh, const unsigned short* __restrict__ xl,
    const unsigned short* __restrict__ bh, const unsigned short* __restrict__ bl,
    float* __restrict__ bias) {
  __shared__ unsigned short sAh[2][128 * 16], sAl[2][128 * 16];
  __shared__ unsigned short sBh[2][128 * 16], sBl[2][128 * 16];
  const int tid = threadIdx.x;
  const int wave = tid >> 6, lane = tid & 63;
  const int wm = wave >> 1, wn = wave & 1;
  const int xcd = blockIdx.x & 7, seq = blockIdx.x >> 3;
  const int mb = xcd * 16 + (seq >> 2);
  const int np = seq & 3;
  const int m0 = mb * 128;
  const int hi32 = lane >> 5;
  const int l31 = lane & 31;

  // staging: thread t stages row t>>1, 16B chunk t&1 (4 KB/array/kt, linear)
  const int srow = tid >> 1;
  const int cch = tid & 1;
  const size_t gA = (size_t)(m0 + srow) * D_DIM + cch * 8;
  const int ldst = tid * 8;

  // fragment read offsets: row-major [128][16], lane row l31, k-half hi32
  int aoff[2], boff[2];
#pragma unroll
  for (int mi = 0; mi < 2; ++mi)
    aoff[mi] = (wm * 64 + mi * 32 + l31) * 16 + hi32 * 8;
#pragma unroll
  for (int ni = 0; ni < 2; ++ni)
    boff[ni] = (wn * 64 + ni * 32 + l31) * 16 + hi32 * 8;

  auto phase = [&](int nb) {
    const int n0 = nb * 128;
    const int k0 = nb * 8;          // triangular: K-range d >= n0, BK=16
    const int ke = 64;
    const size_t gB = (size_t)(n0 + srow) * D_DIM + cch * 8;

    auto stage = [&](int t, int buf) {
      const size_t ko = (size_t)t * 16;
      gload16(xh + gA + ko, &sAh[buf][ldst]);
      gload16(xl + gA + ko, &sAl[buf][ldst]);
      gload16(bh + gB + ko, &sBh[buf][ldst]);
      gload16(bl + gB + ko, &sBl[buf][ldst]);
    };

    f32x16 acc[2][2] = {};
    stage(k0, 0);
    stage(k0 + 1, 1);
    for (int kt = k0; kt < ke; ++kt) {
      const int cur = (kt - k0) & 1;
      if (kt < ke - 1) { VMW(4); } else { VMW(0); }
      BAR;
      {
        bf16x8 fah[2], fal[2], fbh_[2], fbl_[2];
#pragma unroll
        for (int mi = 0; mi < 2; ++mi) {
          fah[mi] = ldfrag(&sAh[cur][aoff[mi]]);
          fal[mi] = ldfrag(&sAl[cur][aoff[mi]]);
        }
#pragma unroll
        for (int ni = 0; ni < 2; ++ni) {
          fbh_[ni] = ldfrag(&sBh[cur][boff[ni]]);
          fbl_[ni] = ldfrag(&sBl[cur][boff[ni]]);
        }
        __builtin_amdgcn_s_setprio(1);
#pragma unroll
        for (int mi = 0; mi < 2; ++mi)
#pragma unroll
          for (int ni = 0; ni < 2; ++ni) {
            acc[mi][ni] = __builtin_amdgcn_mfma_f32_32x32x16_bf16(fah[mi], fbh_[ni], acc[mi][ni], 0, 0, 0);
            acc[mi][ni] = __builtin_amdgcn_mfma_f32_32x32x16_bf16(fah[mi], fbl_[ni], acc[mi][ni], 0, 0, 0);
            acc[mi][ni] = __builtin_amdgcn_mfma_f32_32x32x16_bf16(fal[mi], fbh_[ni], acc[mi][ni], 0, 0, 0);
          }
        __builtin_amdgcn_s_setprio(0);
      }
      BAR;
      if (kt + 2 < ke) stage(kt + 2, cur);
    }

    // fold: p = sum_ni x[row,col_ni] * Y; half-wave reduce; atomicAdd.
#pragma unroll
    for (int mi = 0; mi < 2; ++mi)
#pragma unroll
      for (int r = 0; r < 16; ++r) {
        int row = m0 + wm * 64 + mi * 32 + (r & 3) + 8 * (r >> 2) + 4 * hi32;
        size_t ix = (size_t)row * D_DIM + n0 + wn * 64 + l31;
        float xv0 = bf16_f32(xh[ix]) + bf16_f32(xl[ix]);
        float xv1 = bf16_f32(xh[ix + 32]) + bf16_f32(xl[ix + 32]);
        float p = xv0 * acc[mi][0][r] + xv1 * acc[mi][1][r];
        p += __shfl_xor(p, 1, 64);
        p += __shfl_xor(p, 2, 64);
        p += __shfl_xor(p, 4, 64);
        p += __shfl_xor(p, 8, 64);
        p += __shfl_xor(p, 16, 64);
        if (l31 == 0) atomicAdd(&bias[row], p);
      }
  };

  phase(np);
  phase(7 - np);
}

// =====================================================================
// Q plain-bf16 GEMM with epilogue out[t,e] = S[t] * Q[t,e].
// R6 config: BM=BN=128, 4 waves (2x2), wave 64x64, 1024 blocks,
// LDS 32KB -> 4 blocks/CU, wait-then-barrier vmcnt(4).
// =====================================================================
__global__ __launch_bounds__(256, 4) void k_q_out(
    const unsigned short* __restrict__ xh,
    const unsigned short* __restrict__ qh_,
    const float* __restrict__ S, float* __restrict__ out) {
  __shared__ unsigned short sA[2][128 * 32];
  __shared__ unsigned short sB[2][128 * 32];
  const int tid = threadIdx.x;
  const int wave = tid >> 6, lane = tid & 63;
  const int wm = wave >> 1, wn = wave & 1;
  int sw0 = (blockIdx.x & 7) * 128 + (blockIdx.x >> 3);
  const int mb = sw0 >> 3, nb = sw0 & 7;
  const int m0 = mb * 128, n0 = nb * 128;
  const int hi32 = lane >> 5;
  const int l31 = lane & 31;

  const int srow0 = tid >> 2, srow1 = srow0 + 64;
  const int csrc0 = (tid & 3) ^ swz_row(srow0);
  const int csrc1 = (tid & 3) ^ swz_row(srow1);
  const size_t gaA0 = (size_t)(m0 + srow0) * D_DIM + csrc0 * 8;
  const size_t gaA1 = (size_t)(m0 + srow1) * D_DIM + csrc1 * 8;
  const size_t gaB0 = (size_t)(n0 + srow0) * D_DIM + csrc0 * 8;
  const size_t gaB1 = (size_t)(n0 + srow1) * D_DIM + csrc1 * 8;
  const int ldst0 = tid * 8, ldst1 = (tid + 256) * 8;

  f32x16 acc[2][2] = {};
  int aoff[2][2], boff[2][2];
#pragma unroll
  for (int mi = 0; mi < 2; ++mi) {
    int r = wm * 64 + mi * 32 + l31;
    int sw = swz_row(r);
#pragma unroll
    for (int kh = 0; kh < 2; ++kh)
      aoff[mi][kh] = r * 32 + (((kh * 2 + hi32) ^ sw) * 8);
  }
#pragma unroll
  for (int ni = 0; ni < 2; ++ni) {
    int r = wn * 64 + ni * 32 + l31;
    int sw = swz_row(r);
#pragma unroll
    for (int kh = 0; kh < 2; ++kh)
      boff[ni][kh] = r * 32 + (((kh * 2 + hi32) ^ sw) * 8);
  }

  auto stage = [&](int t, int buf) {
    const size_t ko = (size_t)t * 32;
    gload16(xh + gaA0 + ko, &sA[buf][ldst0]);
    gload16(xh + gaA1 + ko, &sA[buf][ldst1]);
    gload16(qh_ + gaB0 + ko, &sB[buf][ldst0]);
    gload16(qh_ + gaB1 + ko, &sB[buf][ldst1]);
  };

  stage(0, 0);
  stage(1, 1);
  for (int kt = 0; kt < 32; ++kt) {
    const int cur = kt & 1;
    if (kt < 31) { VMW(4); } else { VMW(0); }
    BAR;
#pragma unroll
    for (int kh = 0; kh < 2; ++kh) {
      bf16x8 fa[2], fb[2];
#pragma unroll
      for (int mi = 0; mi < 2; ++mi) fa[mi] = ldfrag(&sA[cur][aoff[mi][kh]]);
#pragma unroll
      for (int ni = 0; ni < 2; ++ni) fb[ni] = ldfrag(&sB[cur][boff[ni][kh]]);
      __builtin_amdgcn_s_setprio(1);
#pragma unroll
      for (int mi = 0; mi < 2; ++mi)
#pragma unroll
        for (int ni = 0; ni < 2; ++ni)
          acc[mi][ni] = __builtin_amdgcn_mfma_f32_32x32x16_bf16(fa[mi], fb[ni], acc[mi][ni], 0, 0, 0);
      __builtin_amdgcn_s_setprio(0);
    }
    BAR;
    if (kt + 2 <= 31) stage(kt + 2, cur);
  }

#pragma unroll
  for (int mi = 0; mi < 2; ++mi)
#pragma unroll
    for (int r = 0; r < 16; ++r) {
      int row = m0 + wm * 64 + mi * 32 + (r & 3) + 8 * (r >> 2) + 4 * hi32;
      float sc = S[row];
      float* orow = out + (size_t)row * D_DIM + n0 + wn * 64 + l31;
      orow[0] = sc * acc[mi][0][r];
      orow[32] = sc * acc[mi][1][r];
    }
}

// =====================================================================
extern "C" void kernel_launch(void* const* d_in, const int* in_sizes, int n_in,
                              void* d_out, int out_size, void* d_ws, size_t ws_size,
                              hipStream_t stream) {
  const float* x   = (const float*)d_in[0];
  const float* Wq  = (const float*)d_in[1];
  const float* Wk  = (const float*)d_in[2];
  const float* Wv  = (const float*)d_in[3];
  const float* Wih = (const float*)d_in[4];
  const float* Whh = (const float*)d_in[5];
  const float* bih = (const float*)d_in[6];
  float* out = (float*)d_out;

  char* ws = (char*)d_ws;
  size_t off = 0;
  auto alloc = [&](size_t bytes) -> char* {
    char* p = ws + off;
    off += (bytes + 255) & ~(size_t)255;
    return p;
  };
  unsigned short* xh   = (unsigned short*)alloc((size_t)M_TOK * D_DIM * 2);
  unsigned short* xl   = (unsigned short*)alloc((size_t)M_TOK * D_DIM * 2);
  unsigned short* wqh  = (unsigned short*)alloc((size_t)D_DIM * D_DIM * 2);
  unsigned short* wkth = (unsigned short*)alloc((size_t)D_DIM * D_DIM * 2);
  unsigned short* wktl = (unsigned short*)alloc((size_t)D_DIM * D_DIM * 2);
  unsigned short* wvth = (unsigned short*)alloc((size_t)D_DIM * D_DIM * 2);
  unsigned short* wvtl = (unsigned short*)alloc((size_t)D_DIM * D_DIM * 2);
  unsigned short* mph  = (unsigned short*)alloc((size_t)D_DIM * D_DIM * 2);
  unsigned short* mpl  = (unsigned short*)alloc((size_t)D_DIM * D_DIM * 2);
  float* Hf   = (float*)alloc((size_t)D_DIM * D_DIM * 4);
  float* bias = (float*)alloc((size_t)M_TOK * 4);
  float* Sbuf = (float*)alloc((size_t)M_TOK * 4);
  float* ubuf = (float*)alloc((size_t)T_DIM * 4);
  float* zbuf = (float*)alloc((size_t)T_DIM * 4);
  // Whh bf16 (8 MB) aliases wkth..wvtl (4 x 2 MB, dead after k_ht).
  unsigned short* whhb = wkth;
  (void)ws_size; (void)in_sizes; (void)n_in; (void)out_size;

  // 1. splits
  k_split<<<2048, 256, 0, stream>>>(x, M_TOK * D_DIM / 8, xh, xl);
  k_split_hi<<<512, 256, 0, stream>>>(Wq, D_DIM * D_DIM / 8, wqh);
  k_split_T<<<256, 256, 0, stream>>>(Wk, wkth, wktl);
  k_split_T<<<256, 256, 0, stream>>>(Wv, wvth, wvtl);

  // 2. zero bias accumulator and h0
  hipMemsetAsync(bias, 0, (size_t)M_TOK * 4, stream);
  hipMemsetAsync(zbuf, 0, (size_t)T_DIM * 4, stream);

  // 3. u vector
  k_u<<<T_DIM / 4, 256, 0, stream>>>(Wih, bih, ubuf);

  // 4. H[d'][d] = sum_e Wv[e,d'] Wk[e,d]  (fp32)
  k_ht<<<256, 256, 0, stream>>>(wvth, wvtl, wkth, wktl, Hf);

  // 5. M' = triangular-weighted symmetrization of H, hi/lo split
  k_nprime<<<256, 256, 0, stream>>>(Hf, mph, mpl);

  // 6. Whh -> bf16 (after k_ht: aliases the transposed weight splits)
  k_split_hi<<<1024, 256, 0, stream>>>(Whh, T_DIM * T_DIM / 8, whhb);

  // 7. Y = x.M' fused into bias (paired triangular grid, BK=16, 4 blk/CU)
  k_y_bias<<<512, 256, 0, stream>>>(xh, xl, mph, mpl, bias);

  // 8. 8-step tanh recurrence over batch rows (wave per row)
  for (int b = 0; b < B_DIM; ++b) {
    const float* hp = (b == 0) ? zbuf : (Sbuf + (size_t)(b - 1) * T_DIM);
    k_step_bf<<<T_DIM / 4, 256, 0, stream>>>(whhb, hp, ubuf, bias + (size_t)b * T_DIM,
                                             Sbuf + (size_t)b * T_DIM);
  }

  // 9. Q GEMM + scale-by-S epilogue
  k_q_out<<<1024, 256, 0, stream>>>(xh, wqh, Sbuf, out);
}

// Round 11
// 267.933 us; speedup vs baseline: 1.0837x; 1.0837x over previous
//
#include <hip/hip_runtime.h>
#include <stdint.h>

#define T_DIM 2048
#define D_DIM 1024
#define B_DIM 8
#define M_TOK (B_DIM * T_DIM)   // 16384 tokens
#define GAMMA_C 0.96875f

typedef float f32x4 __attribute__((ext_vector_type(4)));
typedef float f32x16 __attribute__((ext_vector_type(16)));
typedef float fl4 __attribute__((ext_vector_type(4)));
typedef __bf16 bf16x8 __attribute__((ext_vector_type(8)));
typedef unsigned short us8 __attribute__((ext_vector_type(8)));
typedef unsigned short us4 __attribute__((ext_vector_type(4)));

// ---------- bf16 helpers ----------
__device__ __forceinline__ unsigned short f32_bf16_rne(float f) {
  uint32_t u = __builtin_bit_cast(uint32_t, f);
  return (unsigned short)((u + 0x7FFFu + ((u >> 16) & 1u)) >> 16);
}
__device__ __forceinline__ float bf16_f32(unsigned short h) {
  uint32_t u = ((uint32_t)h) << 16;
  return __builtin_bit_cast(float, u);
}

// chunk swizzle for BK=32 tiles: spreads 32-row b128 column-slice reads
__device__ __forceinline__ int swz_row(int r) {
  return ((r >> 1) & 3) ^ ((r >> 3) & 3);
}

// ---------- global->LDS direct ----------
__device__ __forceinline__ void gload16(const void* g, void* l) {
  __builtin_amdgcn_global_load_lds(
      reinterpret_cast<const __attribute__((address_space(1))) uint32_t*>(
          reinterpret_cast<uintptr_t>(g)),
      reinterpret_cast<__attribute__((address_space(3))) uint32_t*>(
          reinterpret_cast<uintptr_t>(l)),
      16, 0, 0);
}

__device__ __forceinline__ bf16x8 ldfrag(const unsigned short* p) {
  us8 u = *reinterpret_cast<const us8*>(p);
  return __builtin_bit_cast(bf16x8, u);
}

#define VMW(n) asm volatile("s_waitcnt vmcnt(" #n ")" ::: "memory")
#define BAR    __builtin_amdgcn_s_barrier()

// ---------- split f32 -> (hi, lo) bf16, 16B stores ----------
__global__ __launch_bounds__(256) void k_split(const float* __restrict__ in, int n8,
                                               unsigned short* __restrict__ hi,
                                               unsigned short* __restrict__ lo) {
  int stride = gridDim.x * blockDim.x;
  for (int i = blockIdx.x * blockDim.x + threadIdx.x; i < n8; i += stride) {
    fl4 v0 = ((const fl4*)in)[i * 2];
    fl4 v1 = ((const fl4*)in)[i * 2 + 1];
    us8 h, l;
#pragma unroll
    for (int j = 0; j < 4; ++j) {
      unsigned short hb = f32_bf16_rne(v0[j]);
      h[j] = hb;
      l[j] = f32_bf16_rne(v0[j] - bf16_f32(hb));
      unsigned short hb1 = f32_bf16_rne(v1[j]);
      h[j + 4] = hb1;
      l[j + 4] = f32_bf16_rne(v1[j] - bf16_f32(hb1));
    }
    ((us8*)hi)[i] = h;
    ((us8*)lo)[i] = l;
  }
}

__global__ __launch_bounds__(256) void k_split_hi(const float* __restrict__ in, int n8,
                                                  unsigned short* __restrict__ hi) {
  int stride = gridDim.x * blockDim.x;
  for (int i = blockIdx.x * blockDim.x + threadIdx.x; i < n8; i += stride) {
    fl4 v0 = ((const fl4*)in)[i * 2];
    fl4 v1 = ((const fl4*)in)[i * 2 + 1];
    us8 h;
#pragma unroll
    for (int j = 0; j < 4; ++j) {
      h[j] = f32_bf16_rne(v0[j]);
      h[j + 4] = f32_bf16_rne(v1[j]);
    }
    ((us8*)hi)[i] = h;
  }
}

// ---------- transpose-split: out_t[d][e] = split(in[e][d]), 64x64 tiles ----------
__global__ __launch_bounds__(256) void k_split_T(const float* __restrict__ in,
                                                 unsigned short* __restrict__ th,
                                                 unsigned short* __restrict__ tl) {
  __shared__ float tile[64][69];
  int be = blockIdx.x >> 4, bd = blockIdx.x & 15;
  int e0 = be * 64, d0 = bd * 64;
  int r = threadIdx.x >> 4;
  int c = (threadIdx.x & 15) * 4;
#pragma unroll
  for (int it = 0; it < 4; ++it) {
    int rr = r + it * 16;
    fl4 v = *(const fl4*)(in + (size_t)(e0 + rr) * D_DIM + d0 + c);
#pragma unroll
    for (int j = 0; j < 4; ++j) tile[rr][c + j] = v[j];
  }
  __syncthreads();
#pragma unroll
  for (int it = 0; it < 4; ++it) {
    int dr = r + it * 16;
    us4 h, l;
#pragma unroll
    for (int j = 0; j < 4; ++j) {
      float f = tile[c + j][dr];
      h[j] = f32_bf16_rne(f);
      l[j] = f32_bf16_rne(f - bf16_f32(h[j]));
    }
    *(us4*)(th + (size_t)(d0 + dr) * D_DIM + e0 + c) = h;
    *(us4*)(tl + (size_t)(d0 + dr) * D_DIM + e0 + c) = l;
  }
}

// ---------- u[t] = GAMMA * rowsum(W_ih[t,:]) + b_ih[t] ----------
__global__ __launch_bounds__(256) void k_u(const float* __restrict__ Wih,
                                           const float* __restrict__ bih,
                                           float* __restrict__ u) {
  int wave = threadIdx.x >> 6, lane = threadIdx.x & 63;
  int t = blockIdx.x * 4 + wave;
  const fl4* row = (const fl4*)(Wih + (size_t)t * T_DIM);
  float s = 0.f;
#pragma unroll
  for (int i = 0; i < 8; ++i) {
    fl4 v = row[lane + i * 64];
    s += v[0] + v[1] + v[2] + v[3];
  }
#pragma unroll
  for (int m = 32; m >= 1; m >>= 1) s += __shfl_xor(s, m, 64);
  if (lane == 0) u[t] = GAMMA_C * s + bih[t];
}

// ---------- h_out[t] = tanh(u[t] + dot(Whh_bf16[t,:], h_prev) + bias_row[t]) ----------
__global__ __launch_bounds__(256) void k_step_bf(const unsigned short* __restrict__ Whh_b,
                                                 const float* __restrict__ hprev,
                                                 const float* __restrict__ u,
                                                 const float* __restrict__ biasrow,
                                                 float* __restrict__ hout) {
  int wave = threadIdx.x >> 6, lane = threadIdx.x & 63;
  int t = blockIdx.x * 4 + wave;
  const unsigned short* row = Whh_b + (size_t)t * T_DIM;
  float s = 0.f;
#pragma unroll
  for (int i = 0; i < 4; ++i) {
    us8 w = *(const us8*)(row + i * 512 + lane * 8);
    fl4 h0 = *(const fl4*)(hprev + i * 512 + lane * 8);
    fl4 h1 = *(const fl4*)(hprev + i * 512 + lane * 8 + 4);
    s += bf16_f32(w[0]) * h0[0] + bf16_f32(w[1]) * h0[1] +
         bf16_f32(w[2]) * h0[2] + bf16_f32(w[3]) * h0[3] +
         bf16_f32(w[4]) * h1[0] + bf16_f32(w[5]) * h1[1] +
         bf16_f32(w[6]) * h1[2] + bf16_f32(w[7]) * h1[3];
  }
#pragma unroll
  for (int m = 32; m >= 1; m >>= 1) s += __shfl_xor(s, m, 64);
  if (lane == 0) hout[t] = tanhf(u[t] + s + biasrow[t]);
}

// =====================================================================
// H[d'][d] = sum_e Wv[e,d'] * Wk[e,d], 3-term split, fp32 output.
// =====================================================================
__global__ __launch_bounds__(256) void k_ht(
    const unsigned short* __restrict__ ah, const unsigned short* __restrict__ al,
    const unsigned short* __restrict__ bh, const unsigned short* __restrict__ bl,
    float* __restrict__ Hf) {
  __shared__ unsigned short sAh[2][64 * 32], sAl[2][64 * 32];
  __shared__ unsigned short sBh[2][64 * 32], sBl[2][64 * 32];
  const int tid = threadIdx.x;
  const int wave = tid >> 6, lane = tid & 63;
  const int wm = wave >> 1, wn = wave & 1;
  const int m0 = (blockIdx.x >> 4) * 64, n0 = (blockIdx.x & 15) * 64;
  const int hi32 = lane >> 5;

  const int srow = tid >> 2;
  const int csrc = (tid & 3) ^ swz_row(srow);
  const size_t ga = (size_t)(m0 + srow) * D_DIM + csrc * 8;
  const size_t gb = (size_t)(n0 + srow) * D_DIM + csrc * 8;
  const int ldst = tid * 8;

  f32x16 acc = {};
  const int l31 = lane & 31;
  const int sw = swz_row(l31);
  const int ar = wm * 32 + l31;
  const int br = wn * 32 + l31;
  int aoff[2], boff[2];
#pragma unroll
  for (int kh = 0; kh < 2; ++kh) {
    aoff[kh] = ar * 32 + (((kh * 2 + hi32) ^ sw) * 8);
    boff[kh] = br * 32 + (((kh * 2 + hi32) ^ sw) * 8);
  }

  auto stage = [&](int t, int buf) {
    const size_t ko = (size_t)t * 32;
    gload16(ah + ga + ko, &sAh[buf][ldst]);
    gload16(al + ga + ko, &sAl[buf][ldst]);
    gload16(bh + gb + ko, &sBh[buf][ldst]);
    gload16(bl + gb + ko, &sBl[buf][ldst]);
  };

  stage(0, 0);
  stage(1, 1);
  for (int kt = 0; kt < 32; ++kt) {
    const int cur = kt & 1;
    if (kt < 31) { VMW(4); } else { VMW(0); }
    BAR;
#pragma unroll
    for (int kh = 0; kh < 2; ++kh) {
      bf16x8 fah = ldfrag(&sAh[cur][aoff[kh]]);
      bf16x8 fal = ldfrag(&sAl[cur][aoff[kh]]);
      bf16x8 fbh = ldfrag(&sBh[cur][boff[kh]]);
      bf16x8 fbl = ldfrag(&sBl[cur][boff[kh]]);
      acc = __builtin_amdgcn_mfma_f32_32x32x16_bf16(fah, fbh, acc, 0, 0, 0);
      acc = __builtin_amdgcn_mfma_f32_32x32x16_bf16(fah, fbl, acc, 0, 0, 0);
      acc = __builtin_amdgcn_mfma_f32_32x32x16_bf16(fal, fbh, acc, 0, 0, 0);
    }
    BAR;
    if (kt + 2 <= 31) stage(kt + 2, cur);
  }
#pragma unroll
  for (int r = 0; r < 16; ++r) {
    int row = m0 + wm * 32 + (r & 3) + 8 * (r >> 2) + 4 * hi32;
    int col = n0 + wn * 32 + l31;
    Hf[(size_t)row * D_DIM + col] = acc[r];
  }
}

// =====================================================================
// M'[d'][d] = H[d',d]+H[d,d'] (d>d'); H[d,d] (d==d'); 0 (d<d').
// =====================================================================
__global__ __launch_bounds__(256) void k_nprime(const float* __restrict__ Hf,
                                                unsigned short* __restrict__ mh,
                                                unsigned short* __restrict__ ml) {
  __shared__ float t2[64][65];
  const int ti = blockIdx.x >> 4;
  const int tj = blockIdx.x & 15;
  const int r0 = ti * 64, c0 = tj * 64;
  const int a = threadIdx.x >> 2;
  const int b4 = (threadIdx.x & 3) * 16;
  if (tj < ti) {
#pragma unroll
    for (int j = 0; j < 16; ++j) {
      size_t ad = (size_t)(r0 + a) * D_DIM + c0 + b4 + j;
      mh[ad] = 0;
      ml[ad] = 0;
    }
    return;
  }
#pragma unroll
  for (int j = 0; j < 16; j += 4) {
    fl4 v = *(const fl4*)(Hf + (size_t)(c0 + a) * D_DIM + r0 + b4 + j);
#pragma unroll
    for (int q = 0; q < 4; ++q) t2[a][b4 + j + q] = v[q];
  }
  __syncthreads();
#pragma unroll
  for (int j = 0; j < 16; ++j) {
    int dp = r0 + a;
    int dd = c0 + b4 + j;
    float v = 0.f;
    if (dd > dp)       v = Hf[(size_t)dp * D_DIM + dd] + t2[b4 + j][a];
    else if (dd == dp) v = Hf[(size_t)dp * D_DIM + dd];
    unsigned short hb = f32_bf16_rne(v);
    unsigned short lb = f32_bf16_rne(v - bf16_f32(hb));
    size_t ad = (size_t)dp * D_DIM + dd;
    mh[ad] = hb;
    ml[ad] = lb;
  }
}

// =====================================================================
// Y = x.M'^T fused bias — R1 structure (the session's best MFMA feeder):
//   512 thr / 8 waves (2m x 4n), wave 64x32, BM=BN=128, BK=32,
//   4 arrays x 3 BUFFERS = 96 KB LDS (1 blk/CU), MFMA 32x32x16, 3-term.
//   ONE barrier per kt: VMW(4); BAR; stage(kt+2, cur+2 mod 3); compute(cur).
//   Safety: at BAR(kt), every wave's ds_reads of tile kt-1 completed
//   (consumed by MFMAs issued pre-barrier) -> restaging that buffer is
//   safe; VMW(4)+BAR proves tile kt fully staged by ALL waves.
//   Inter-phase BAR fences phase-2 restage of buf0 against phase-1's
//   final compute (race surface R1 didn't have).
//   Triangular pairing {np, 7-np}: 36 kt/block, 512 blocks (one round).
// =====================================================================
__global__ __launch_bounds__(512, 2) void k_y_bias(
    const unsigned short* __restrict__ xh, const unsigned short* __restrict__ xl,
    const unsigned short* __restrict__ bh, const unsigned short* __restrict__ bl,
    float* __restrict__ bias) {
  __shared__ unsigned short sAh[3][128 * 32], sAl[3][128 * 32];
  __shared__ unsigned short sBh[3][128 * 32], sBl[3][128 * 32];
  const int tid = threadIdx.x;
  const int wave = tid >> 6, lane = tid & 63;
  const int wm = wave >> 2, wn = wave & 3;
  const int xcd = blockIdx.x & 7, seq = blockIdx.x >> 3;
  const int mb = xcd * 16 + (seq >> 2);
  const int np = seq & 3;
  const int m0 = mb * 128;
  const int hi32 = lane >> 5;
  const int l31 = lane & 31;

  // staging: 512 threads cover 128 rows x 32 cols per array (16B each)
  const int srow = tid >> 2;
  const int csrc = (tid & 3) ^ swz_row(srow);
  const size_t gA = (size_t)(m0 + srow) * D_DIM + csrc * 8;
  const int ldst = tid * 8;

  // fragment offsets: wave tile 64x32 -> A rows wm*64+mi*32, B rows wn*32
  int aoff[2][2], boff[2];
#pragma unroll
  for (int mi = 0; mi < 2; ++mi) {
    int r = wm * 64 + mi * 32 + l31;
    int sw = swz_row(r);
#pragma unroll
    for (int kh = 0; kh < 2; ++kh)
      aoff[mi][kh] = r * 32 + (((kh * 2 + hi32) ^ sw) * 8);
  }
  {
    int r = wn * 32 + l31;
    int sw = swz_row(r);
#pragma unroll
    for (int kh = 0; kh < 2; ++kh)
      boff[kh] = r * 32 + (((kh * 2 + hi32) ^ sw) * 8);
  }

  auto phase = [&](int nb) {
    const int n0 = nb * 128;
    const int k0 = nb * 4, ke = 32;
    const size_t gB = (size_t)(n0 + srow) * D_DIM + csrc * 8;

    auto stage = [&](int t, int buf) {
      const size_t ko = (size_t)t * 32;
      gload16(xh + gA + ko, &sAh[buf][ldst]);
      gload16(xl + gA + ko, &sAl[buf][ldst]);
      gload16(bh + gB + ko, &sBh[buf][ldst]);
      gload16(bl + gB + ko, &sBl[buf][ldst]);
    };

    f32x16 acc[2] = {};
    BAR;                          // fence prev phase's last reads vs restage
    stage(k0, 0);
    stage(k0 + 1, 1);
    int cur = 0;
    for (int kt = k0; kt < ke; ++kt) {
      if (kt < ke - 1) { VMW(4); } else { VMW(0); }
      BAR;
      int nx = cur + 2; if (nx >= 3) nx -= 3;
      if (kt + 2 < ke) stage(kt + 2, nx);
#pragma unroll
      for (int kh = 0; kh < 2; ++kh) {
        bf16x8 fah[2], fal[2];
#pragma unroll
        for (int mi = 0; mi < 2; ++mi) {
          fah[mi] = ldfrag(&sAh[cur][aoff[mi][kh]]);
          fal[mi] = ldfrag(&sAl[cur][aoff[mi][kh]]);
        }
        bf16x8 fbh = ldfrag(&sBh[cur][boff[kh]]);
        bf16x8 fbl = ldfrag(&sBl[cur][boff[kh]]);
        __builtin_amdgcn_s_setprio(1);
#pragma unroll
        for (int mi = 0; mi < 2; ++mi) {
          acc[mi] = __builtin_amdgcn_mfma_f32_32x32x16_bf16(fah[mi], fbh, acc[mi], 0, 0, 0);
          acc[mi] = __builtin_amdgcn_mfma_f32_32x32x16_bf16(fah[mi], fbl, acc[mi], 0, 0, 0);
          acc[mi] = __builtin_amdgcn_mfma_f32_32x32x16_bf16(fal[mi], fbh, acc[mi], 0, 0, 0);
        }
        __builtin_amdgcn_s_setprio(0);
      }
      cur = cur + 1; if (cur >= 3) cur -= 3;
    }

    // fold: p = x[row,col] * Y; 32-lane reduce; atomicAdd. x from warm xh+xl.
#pragma unroll
    for (int mi = 0; mi < 2; ++mi)
#pragma unroll
      for (int r = 0; r < 16; ++r) {
        int row = m0 + wm * 64 + mi * 32 + (r & 3) + 8 * (r >> 2) + 4 * hi32;
        size_t ix = (size_t)row * D_DIM + n0 + wn * 32 + l31;
        float xv = bf16_f32(xh[ix]) + bf16_f32(xl[ix]);
        float p = xv * acc[mi][r];
        p += __shfl_xor(p, 1, 64);
        p += __shfl_xor(p, 2, 64);
        p += __shfl_xor(p, 4, 64);
        p += __shfl_xor(p, 8, 64);
        p += __shfl_xor(p, 16, 64);
        if (l31 == 0) atomicAdd(&bias[row], p);
      }
  };

  phase(np);
  phase(7 - np);
}

// =====================================================================
// Q plain-bf16 GEMM with epilogue out[t,e] = S[t] * Q[t,e].
// R6 config (in the 236us run): BM=BN=128, 4 waves (2x2), wave 64x64,
// 1024 blocks, LDS 32KB -> 4 blocks/CU, wait-then-barrier vmcnt(4).
// =====================================================================
__global__ __launch_bounds__(256, 4) void k_q_out(
    const unsigned short* __restrict__ xh,
    const unsigned short* __restrict__ qh_,
    const float* __restrict__ S, float* __restrict__ out) {
  __shared__ unsigned short sA[2][128 * 32];
  __shared__ unsigned short sB[2][128 * 32];
  const int tid = threadIdx.x;
  const int wave = tid >> 6, lane = tid & 63;
  const int wm = wave >> 1, wn = wave & 1;
  int sw0 = (blockIdx.x & 7) * 128 + (blockIdx.x >> 3);
  const int mb = sw0 >> 3, nb = sw0 & 7;
  const int m0 = mb * 128, n0 = nb * 128;
  const int hi32 = lane >> 5;
  const int l31 = lane & 31;

  const int srow0 = tid >> 2, srow1 = srow0 + 64;
  const int csrc0 = (tid & 3) ^ swz_row(srow0);
  const int csrc1 = (tid & 3) ^ swz_row(srow1);
  const size_t gaA0 = (size_t)(m0 + srow0) * D_DIM + csrc0 * 8;
  const size_t gaA1 = (size_t)(m0 + srow1) * D_DIM + csrc1 * 8;
  const size_t gaB0 = (size_t)(n0 + srow0) * D_DIM + csrc0 * 8;
  const size_t gaB1 = (size_t)(n0 + srow1) * D_DIM + csrc1 * 8;
  const int ldst0 = tid * 8, ldst1 = (tid + 256) * 8;

  f32x16 acc[2][2] = {};
  int aoff[2][2], boff[2][2];
#pragma unroll
  for (int mi = 0; mi < 2; ++mi) {
    int r = wm * 64 + mi * 32 + l31;
    int sw = swz_row(r);
#pragma unroll
    for (int kh = 0; kh < 2; ++kh)
      aoff[mi][kh] = r * 32 + (((kh * 2 + hi32) ^ sw) * 8);
  }
#pragma unroll
  for (int ni = 0; ni < 2; ++ni) {
    int r = wn * 64 + ni * 32 + l31;
    int sw = swz_row(r);
#pragma unroll
    for (int kh = 0; kh < 2; ++kh)
      boff[ni][kh] = r * 32 + (((kh * 2 + hi32) ^ sw) * 8);
  }

  auto stage = [&](int t, int buf) {
    const size_t ko = (size_t)t * 32;
    gload16(xh + gaA0 + ko, &sA[buf][ldst0]);
    gload16(xh + gaA1 + ko, &sA[buf][ldst1]);
    gload16(qh_ + gaB0 + ko, &sB[buf][ldst0]);
    gload16(qh_ + gaB1 + ko, &sB[buf][ldst1]);
  };

  stage(0, 0);
  stage(1, 1);
  for (int kt = 0; kt < 32; ++kt) {
    const int cur = kt & 1;
    if (kt < 31) { VMW(4); } else { VMW(0); }
    BAR;
#pragma unroll
    for (int kh = 0; kh < 2; ++kh) {
      bf16x8 fa[2], fb[2];
#pragma unroll
      for (int mi = 0; mi < 2; ++mi) fa[mi] = ldfrag(&sA[cur][aoff[mi][kh]]);
#pragma unroll
      for (int ni = 0; ni < 2; ++ni) fb[ni] = ldfrag(&sB[cur][boff[ni][kh]]);
      __builtin_amdgcn_s_setprio(1);
#pragma unroll
      for (int mi = 0; mi < 2; ++mi)
#pragma unroll
        for (int ni = 0; ni < 2; ++ni)
          acc[mi][ni] = __builtin_amdgcn_mfma_f32_32x32x16_bf16(fa[mi], fb[ni], acc[mi][ni], 0, 0, 0);
      __builtin_amdgcn_s_setprio(0);
    }
    BAR;
    if (kt + 2 <= 31) stage(kt + 2, cur);
  }

#pragma unroll
  for (int mi = 0; mi < 2; ++mi)
#pragma unroll
    for (int r = 0; r < 16; ++r) {
      int row = m0 + wm * 64 + mi * 32 + (r & 3) + 8 * (r >> 2) + 4 * hi32;
      float sc = S[row];
      float* orow = out + (size_t)row * D_DIM + n0 + wn * 64 + l31;
      orow[0] = sc * acc[mi][0][r];
      orow[32] = sc * acc[mi][1][r];
    }
}

// =====================================================================
extern "C" void kernel_launch(void* const* d_in, const int* in_sizes, int n_in,
                              void* d_out, int out_size, void* d_ws, size_t ws_size,
                              hipStream_t stream) {
  const float* x   = (const float*)d_in[0];
  const float* Wq  = (const float*)d_in[1];
  const float* Wk  = (const float*)d_in[2];
  const float* Wv  = (const float*)d_in[3];
  const float* Wih = (const float*)d_in[4];
  const float* Whh = (const float*)d_in[5];
  const float* bih = (const float*)d_in[6];
  float* out = (float*)d_out;

  char* ws = (char*)d_ws;
  size_t off = 0;
  auto alloc = [&](size_t bytes) -> char* {
    char* p = ws + off;
    off += (bytes + 255) & ~(size_t)255;
    return p;
  };
  unsigned short* xh   = (unsigned short*)alloc((size_t)M_TOK * D_DIM * 2);
  unsigned short* xl   = (unsigned short*)alloc((size_t)M_TOK * D_DIM * 2);
  unsigned short* wqh  = (unsigned short*)alloc((size_t)D_DIM * D_DIM * 2);
  unsigned short* wkth = (unsigned short*)alloc((size_t)D_DIM * D_DIM * 2);
  unsigned short* wktl = (unsigned short*)alloc((size_t)D_DIM * D_DIM * 2);
  unsigned short* wvth = (unsigned short*)alloc((size_t)D_DIM * D_DIM * 2);
  unsigned short* wvtl = (unsigned short*)alloc((size_t)D_DIM * D_DIM * 2);
  unsigned short* mph  = (unsigned short*)alloc((size_t)D_DIM * D_DIM * 2);
  unsigned short* mpl  = (unsigned short*)alloc((size_t)D_DIM * D_DIM * 2);
  float* Hf   = (float*)alloc((size_t)D_DIM * D_DIM * 4);
  float* bias = (float*)alloc((size_t)M_TOK * 4);
  float* Sbuf = (float*)alloc((size_t)M_TOK * 4);
  float* ubuf = (float*)alloc((size_t)T_DIM * 4);
  float* zbuf = (float*)alloc((size_t)T_DIM * 4);
  // Whh bf16 (8 MB) aliases wkth..wvtl (4 x 2 MB, dead after k_ht).
  unsigned short* whhb = wkth;
  (void)ws_size; (void)in_sizes; (void)n_in; (void)out_size;

  // 1. splits
  k_split<<<2048, 256, 0, stream>>>(x, M_TOK * D_DIM / 8, xh, xl);
  k_split_hi<<<512, 256, 0, stream>>>(Wq, D_DIM * D_DIM / 8, wqh);
  k_split_T<<<256, 256, 0, stream>>>(Wk, wkth, wktl);
  k_split_T<<<256, 256, 0, stream>>>(Wv, wvth, wvtl);

  // 2. zero bias accumulator and h0
  hipMemsetAsync(bias, 0, (size_t)M_TOK * 4, stream);
  hipMemsetAsync(zbuf, 0, (size_t)T_DIM * 4, stream);

  // 3. u vector
  k_u<<<T_DIM / 4, 256, 0, stream>>>(Wih, bih, ubuf);

  // 4. H[d'][d] = sum_e Wv[e,d'] Wk[e,d]  (fp32)
  k_ht<<<256, 256, 0, stream>>>(wvth, wvtl, wkth, wktl, Hf);

  // 5. M' = triangular-weighted symmetrization of H, hi/lo split
  k_nprime<<<256, 256, 0, stream>>>(Hf, mph, mpl);

  // 6. Whh -> bf16 (after k_ht: aliases the transposed weight splits)
  k_split_hi<<<1024, 256, 0, stream>>>(Whh, T_DIM * T_DIM / 8, whhb);

  // 7. Y = x.M' fused into bias (R1 structure: 3-buf, 1 barrier/kt)
  k_y_bias<<<512, 512, 0, stream>>>(xh, xl, mph, mpl, bias);

  // 8. 8-step tanh recurrence over batch rows (wave per row)
  for (int b = 0; b < B_DIM; ++b) {
    const float* hp = (b == 0) ? zbuf : (Sbuf + (size_t)(b - 1) * T_DIM);
    k_step_bf<<<T_DIM / 4, 256, 0, stream>>>(whhb, hp, ubuf, bias + (size_t)b * T_DIM,
                                             Sbuf + (size_t)b * T_DIM);
  }

  // 9. Q GEMM + scale-by-S epilogue
  k_q_out<<<1024, 256, 0, stream>>>(xh, wqh, Sbuf, out);
}

// Round 12
// 244.547 us; speedup vs baseline: 1.1873x; 1.0956x over previous
//
#include <hip/hip_runtime.h>
#include <stdint.h>

#define T_DIM 2048
#define D_DIM 1024
#define B_DIM 8
#define M_TOK (B_DIM * T_DIM)   // 16384 tokens
#define GAMMA_C 0.96875f

typedef float f32x4 __attribute__((ext_vector_type(4)));
typedef float f32x16 __attribute__((ext_vector_type(16)));
typedef float fl4 __attribute__((ext_vector_type(4)));
typedef __bf16 bf16x8 __attribute__((ext_vector_type(8)));
typedef unsigned short us8 __attribute__((ext_vector_type(8)));
typedef unsigned short us4 __attribute__((ext_vector_type(4)));

// ---------- bf16 helpers ----------
__device__ __forceinline__ unsigned short f32_bf16_rne(float f) {
  uint32_t u = __builtin_bit_cast(uint32_t, f);
  return (unsigned short)((u + 0x7FFFu + ((u >> 16) & 1u)) >> 16);
}
__device__ __forceinline__ float bf16_f32(unsigned short h) {
  uint32_t u = ((uint32_t)h) << 16;
  return __builtin_bit_cast(float, u);
}

// chunk swizzle: spreads fragment column-slice reads across bank groups
__device__ __forceinline__ int swz_row(int r) {
  return ((r >> 1) & 3) ^ ((r >> 3) & 3);
}

// ---------- global->LDS direct ----------
__device__ __forceinline__ void gload16(const void* g, void* l) {
  __builtin_amdgcn_global_load_lds(
      reinterpret_cast<const __attribute__((address_space(1))) uint32_t*>(
          reinterpret_cast<uintptr_t>(g)),
      reinterpret_cast<__attribute__((address_space(3))) uint32_t*>(
          reinterpret_cast<uintptr_t>(l)),
      16, 0, 0);
}

__device__ __forceinline__ bf16x8 ldfrag(const unsigned short* p) {
  us8 u = *reinterpret_cast<const us8*>(p);
  return __builtin_bit_cast(bf16x8, u);
}

#define VMW(n) asm volatile("s_waitcnt vmcnt(" #n ")" ::: "memory")
#define BAR    __builtin_amdgcn_s_barrier()

// ---------- split f32 -> (hi, lo) bf16, 16B stores ----------
__global__ __launch_bounds__(256) void k_split(const float* __restrict__ in, int n8,
                                               unsigned short* __restrict__ hi,
                                               unsigned short* __restrict__ lo) {
  int stride = gridDim.x * blockDim.x;
  for (int i = blockIdx.x * blockDim.x + threadIdx.x; i < n8; i += stride) {
    fl4 v0 = ((const fl4*)in)[i * 2];
    fl4 v1 = ((const fl4*)in)[i * 2 + 1];
    us8 h, l;
#pragma unroll
    for (int j = 0; j < 4; ++j) {
      unsigned short hb = f32_bf16_rne(v0[j]);
      h[j] = hb;
      l[j] = f32_bf16_rne(v0[j] - bf16_f32(hb));
      unsigned short hb1 = f32_bf16_rne(v1[j]);
      h[j + 4] = hb1;
      l[j + 4] = f32_bf16_rne(v1[j] - bf16_f32(hb1));
    }
    ((us8*)hi)[i] = h;
    ((us8*)lo)[i] = l;
  }
}

__global__ __launch_bounds__(256) void k_split_hi(const float* __restrict__ in, int n8,
                                                  unsigned short* __restrict__ hi) {
  int stride = gridDim.x * blockDim.x;
  for (int i = blockIdx.x * blockDim.x + threadIdx.x; i < n8; i += stride) {
    fl4 v0 = ((const fl4*)in)[i * 2];
    fl4 v1 = ((const fl4*)in)[i * 2 + 1];
    us8 h;
#pragma unroll
    for (int j = 0; j < 4; ++j) {
      h[j] = f32_bf16_rne(v0[j]);
      h[j + 4] = f32_bf16_rne(v1[j]);
    }
    ((us8*)hi)[i] = h;
  }
}

// ---------- transpose-split: out_t[d][e] = split(in[e][d]), 64x64 tiles ----------
__global__ __launch_bounds__(256) void k_split_T(const float* __restrict__ in,
                                                 unsigned short* __restrict__ th,
                                                 unsigned short* __restrict__ tl) {
  __shared__ float tile[64][69];
  int be = blockIdx.x >> 4, bd = blockIdx.x & 15;
  int e0 = be * 64, d0 = bd * 64;
  int r = threadIdx.x >> 4;
  int c = (threadIdx.x & 15) * 4;
#pragma unroll
  for (int it = 0; it < 4; ++it) {
    int rr = r + it * 16;
    fl4 v = *(const fl4*)(in + (size_t)(e0 + rr) * D_DIM + d0 + c);
#pragma unroll
    for (int j = 0; j < 4; ++j) tile[rr][c + j] = v[j];
  }
  __syncthreads();
#pragma unroll
  for (int it = 0; it < 4; ++it) {
    int dr = r + it * 16;
    us4 h, l;
#pragma unroll
    for (int j = 0; j < 4; ++j) {
      float f = tile[c + j][dr];
      h[j] = f32_bf16_rne(f);
      l[j] = f32_bf16_rne(f - bf16_f32(h[j]));
    }
    *(us4*)(th + (size_t)(d0 + dr) * D_DIM + e0 + c) = h;
    *(us4*)(tl + (size_t)(d0 + dr) * D_DIM + e0 + c) = l;
  }
}

// ---------- u[t] = GAMMA * rowsum(W_ih[t,:]) + b_ih[t] ----------
__global__ __launch_bounds__(256) void k_u(const float* __restrict__ Wih,
                                           const float* __restrict__ bih,
                                           float* __restrict__ u) {
  int wave = threadIdx.x >> 6, lane = threadIdx.x & 63;
  int t = blockIdx.x * 4 + wave;
  const fl4* row = (const fl4*)(Wih + (size_t)t * T_DIM);
  float s = 0.f;
#pragma unroll
  for (int i = 0; i < 8; ++i) {
    fl4 v = row[lane + i * 64];
    s += v[0] + v[1] + v[2] + v[3];
  }
#pragma unroll
  for (int m = 32; m >= 1; m >>= 1) s += __shfl_xor(s, m, 64);
  if (lane == 0) u[t] = GAMMA_C * s + bih[t];
}

// ---------- h_out[t] = tanh(u[t] + dot(Whh_bf16[t,:], h_prev) + bias_row[t]) ----------
__global__ __launch_bounds__(256) void k_step_bf(const unsigned short* __restrict__ Whh_b,
                                                 const float* __restrict__ hprev,
                                                 const float* __restrict__ u,
                                                 const float* __restrict__ biasrow,
                                                 float* __restrict__ hout) {
  int wave = threadIdx.x >> 6, lane = threadIdx.x & 63;
  int t = blockIdx.x * 4 + wave;
  const unsigned short* row = Whh_b + (size_t)t * T_DIM;
  float s = 0.f;
#pragma unroll
  for (int i = 0; i < 4; ++i) {
    us8 w = *(const us8*)(row + i * 512 + lane * 8);
    fl4 h0 = *(const fl4*)(hprev + i * 512 + lane * 8);
    fl4 h1 = *(const fl4*)(hprev + i * 512 + lane * 8 + 4);
    s += bf16_f32(w[0]) * h0[0] + bf16_f32(w[1]) * h0[1] +
         bf16_f32(w[2]) * h0[2] + bf16_f32(w[3]) * h0[3] +
         bf16_f32(w[4]) * h1[0] + bf16_f32(w[5]) * h1[1] +
         bf16_f32(w[6]) * h1[2] + bf16_f32(w[7]) * h1[3];
  }
#pragma unroll
  for (int m = 32; m >= 1; m >>= 1) s += __shfl_xor(s, m, 64);
  if (lane == 0) hout[t] = tanhf(u[t] + s + biasrow[t]);
}

// =====================================================================
// H[d'][d] = sum_e Wv[e,d'] * Wk[e,d], 3-term split, fp32 output.
// =====================================================================
__global__ __launch_bounds__(256) void k_ht(
    const unsigned short* __restrict__ ah, const unsigned short* __restrict__ al,
    const unsigned short* __restrict__ bh, const unsigned short* __restrict__ bl,
    float* __restrict__ Hf) {
  __shared__ unsigned short sAh[2][64 * 32], sAl[2][64 * 32];
  __shared__ unsigned short sBh[2][64 * 32], sBl[2][64 * 32];
  const int tid = threadIdx.x;
  const int wave = tid >> 6, lane = tid & 63;
  const int wm = wave >> 1, wn = wave & 1;
  const int m0 = (blockIdx.x >> 4) * 64, n0 = (blockIdx.x & 15) * 64;
  const int hi32 = lane >> 5;

  const int srow = tid >> 2;
  const int csrc = (tid & 3) ^ swz_row(srow);
  const size_t ga = (size_t)(m0 + srow) * D_DIM + csrc * 8;
  const size_t gb = (size_t)(n0 + srow) * D_DIM + csrc * 8;
  const int ldst = tid * 8;

  f32x16 acc = {};
  const int l31 = lane & 31;
  const int sw = swz_row(l31);
  const int ar = wm * 32 + l31;
  const int br = wn * 32 + l31;
  int aoff[2], boff[2];
#pragma unroll
  for (int kh = 0; kh < 2; ++kh) {
    aoff[kh] = ar * 32 + (((kh * 2 + hi32) ^ sw) * 8);
    boff[kh] = br * 32 + (((kh * 2 + hi32) ^ sw) * 8);
  }

  auto stage = [&](int t, int buf) {
    const size_t ko = (size_t)t * 32;
    gload16(ah + ga + ko, &sAh[buf][ldst]);
    gload16(al + ga + ko, &sAl[buf][ldst]);
    gload16(bh + gb + ko, &sBh[buf][ldst]);
    gload16(bl + gb + ko, &sBl[buf][ldst]);
  };

  stage(0, 0);
  stage(1, 1);
  for (int kt = 0; kt < 32; ++kt) {
    const int cur = kt & 1;
    if (kt < 31) { VMW(4); } else { VMW(0); }
    BAR;
#pragma unroll
    for (int kh = 0; kh < 2; ++kh) {
      bf16x8 fah = ldfrag(&sAh[cur][aoff[kh]]);
      bf16x8 fal = ldfrag(&sAl[cur][aoff[kh]]);
      bf16x8 fbh = ldfrag(&sBh[cur][boff[kh]]);
      bf16x8 fbl = ldfrag(&sBl[cur][boff[kh]]);
      acc = __builtin_amdgcn_mfma_f32_32x32x16_bf16(fah, fbh, acc, 0, 0, 0);
      acc = __builtin_amdgcn_mfma_f32_32x32x16_bf16(fah, fbl, acc, 0, 0, 0);
      acc = __builtin_amdgcn_mfma_f32_32x32x16_bf16(fal, fbh, acc, 0, 0, 0);
    }
    BAR;
    if (kt + 2 <= 31) stage(kt + 2, cur);
  }
#pragma unroll
  for (int r = 0; r < 16; ++r) {
    int row = m0 + wm * 32 + (r & 3) + 8 * (r >> 2) + 4 * hi32;
    int col = n0 + wn * 32 + l31;
    Hf[(size_t)row * D_DIM + col] = acc[r];
  }
}

// =====================================================================
// M'[d'][d] = H[d',d]+H[d,d'] (d>d'); H[d,d] (d==d'); 0 (d<d').
// =====================================================================
__global__ __launch_bounds__(256) void k_nprime(const float* __restrict__ Hf,
                                                unsigned short* __restrict__ mh,
                                                unsigned short* __restrict__ ml) {
  __shared__ float t2[64][65];
  const int ti = blockIdx.x >> 4;
  const int tj = blockIdx.x & 15;
  const int r0 = ti * 64, c0 = tj * 64;
  const int a = threadIdx.x >> 2;
  const int b4 = (threadIdx.x & 3) * 16;
  if (tj < ti) {
#pragma unroll
    for (int j = 0; j < 16; ++j) {
      size_t ad = (size_t)(r0 + a) * D_DIM + c0 + b4 + j;
      mh[ad] = 0;
      ml[ad] = 0;
    }
    return;
  }
#pragma unroll
  for (int j = 0; j < 16; j += 4) {
    fl4 v = *(const fl4*)(Hf + (size_t)(c0 + a) * D_DIM + r0 + b4 + j);
#pragma unroll
    for (int q = 0; q < 4; ++q) t2[a][b4 + j + q] = v[q];
  }
  __syncthreads();
#pragma unroll
  for (int j = 0; j < 16; ++j) {
    int dp = r0 + a;
    int dd = c0 + b4 + j;
    float v = 0.f;
    if (dd > dp)       v = Hf[(size_t)dp * D_DIM + dd] + t2[b4 + j][a];
    else if (dd == dp) v = Hf[(size_t)dp * D_DIM + dd];
    unsigned short hb = f32_bf16_rne(v);
    unsigned short lb = f32_bf16_rne(v - bf16_f32(hb));
    size_t ad = (size_t)dp * D_DIM + dd;
    mh[ad] = hb;
    ml[ad] = lb;
  }
}

// =====================================================================
// Y = x.M'^T fused bias — R1 geometry (48 MFMA/wave/kt, the session's
// best barrier-amortization) + triangular M' + one-barrier 3-buf rotation:
//   512 thr / 8 waves (2m x 4n), wave 64x64 in 16x16x32 frags
//   (mi=4, ni=4 -> 48 MFMA-instr per wave per kt, ~230 cyc/sync).
//   BM=128, BN=256, BK=32. LDS 3buf x (A 16KB + B 32KB) = 144 KB, 1 blk/CU.
//   Schedule per kt: VMW(6); BAR; stage(kt+2 -> buf[kt-1]); compute(cur).
//   Safety: at BAR all waves' tile-kt loads landed AND their kt-1 frag
//   reads retired (consumed by pre-barrier MFMAs) -> restage is safe.
//   Triangular K-split, 256 blocks x exactly 40 kt (one dispatch round):
//   half0 = nb0[0,32) + nb1[8,16); half1 = nb1[16,32)+nb2[16,32)+nb3[24,32).
//   Partial-K fold is exact (fold linear in Y; atomicAdd sums).
// =====================================================================
__global__ __launch_bounds__(512, 2) void k_y_bias(
    const unsigned short* __restrict__ xh, const unsigned short* __restrict__ xl,
    const unsigned short* __restrict__ bh, const unsigned short* __restrict__ bl,
    float* __restrict__ bias) {
  __shared__ unsigned short sAh[3][128 * 32], sAl[3][128 * 32];
  __shared__ unsigned short sBh[3][256 * 32], sBl[3][256 * 32];
  const int tid = threadIdx.x;
  const int wave = tid >> 6, lane = tid & 63;
  const int wm = wave >> 2;      // 0..1
  const int wn = wave & 3;       // 0..3
  const int xcd = blockIdx.x & 7, seq = blockIdx.x >> 3;
  const int mb = xcd * 16 + (seq >> 1);
  const int half = seq & 1;
  const int m0 = mb * 128;
  const int l15 = lane & 15;
  const int kc = lane >> 4;      // k-chunk 0..3 for 16x16x32 A/B frags

  // staging: A = 1 pass (rows 0..127), B = 2 passes (rows 0..255)
  const int srow = tid >> 2;
  const int csrc = (tid & 3) ^ swz_row(srow);   // swz_row(r+128)==swz_row(r)
  const size_t gA = (size_t)(m0 + srow) * D_DIM + csrc * 8;
  const int ldstA = tid * 8;
  const int ldstB0 = tid * 8, ldstB1 = (tid + 512) * 8;

  // fragment read offsets: row ra/rb, logical chunk kc, phys = kc ^ swz(row)
  int aoff[4], boff[4];
#pragma unroll
  for (int mi = 0; mi < 4; ++mi) {
    int r = wm * 64 + mi * 16 + l15;
    aoff[mi] = r * 32 + ((kc ^ swz_row(r)) * 8);
  }
#pragma unroll
  for (int ni = 0; ni < 4; ++ni) {
    int r = wn * 64 + ni * 16 + l15;
    boff[ni] = r * 32 + ((kc ^ swz_row(r)) * 8);
  }

  auto phase = [&](int nb, int k0, int ke) {
    const int n0 = nb * 256;
    const size_t gB0 = (size_t)(n0 + srow) * D_DIM + csrc * 8;
    const size_t gB1 = (size_t)(n0 + srow + 128) * D_DIM + csrc * 8;

    auto stage = [&](int t, int buf) {
      const size_t ko = (size_t)t * 32;
      gload16(xh + gA + ko, &sAh[buf][ldstA]);
      gload16(xl + gA + ko, &sAl[buf][ldstA]);
      gload16(bh + gB0 + ko, &sBh[buf][ldstB0]);
      gload16(bh + gB1 + ko, &sBh[buf][ldstB1]);
      gload16(bl + gB0 + ko, &sBl[buf][ldstB0]);
      gload16(bl + gB1 + ko, &sBl[buf][ldstB1]);
    };

    f32x4 acc[4][4] = {};
    BAR;                          // fence prev phase's reads vs restage
    stage(k0, 0);
    stage(k0 + 1, 1);
    int cur = 0;
    for (int kt = k0; kt < ke; ++kt) {
      if (kt < ke - 1) { VMW(6); } else { VMW(0); }
      BAR;
      int nx = cur + 2; if (nx >= 3) nx -= 3;
      if (kt + 2 < ke) stage(kt + 2, nx);
      {
        bf16x8 fah[4], fal[4], fbh_[4], fbl_[4];
#pragma unroll
        for (int mi = 0; mi < 4; ++mi) {
          fah[mi] = ldfrag(&sAh[cur][aoff[mi]]);
          fal[mi] = ldfrag(&sAl[cur][aoff[mi]]);
        }
#pragma unroll
        for (int ni = 0; ni < 4; ++ni) {
          fbh_[ni] = ldfrag(&sBh[cur][boff[ni]]);
          fbl_[ni] = ldfrag(&sBl[cur][boff[ni]]);
        }
        __builtin_amdgcn_s_setprio(1);
#pragma unroll
        for (int mi = 0; mi < 4; ++mi)
#pragma unroll
          for (int ni = 0; ni < 4; ++ni) {
            acc[mi][ni] = __builtin_amdgcn_mfma_f32_16x16x32_bf16(fah[mi], fbh_[ni], acc[mi][ni], 0, 0, 0);
            acc[mi][ni] = __builtin_amdgcn_mfma_f32_16x16x32_bf16(fah[mi], fbl_[ni], acc[mi][ni], 0, 0, 0);
            acc[mi][ni] = __builtin_amdgcn_mfma_f32_16x16x32_bf16(fal[mi], fbh_[ni], acc[mi][ni], 0, 0, 0);
          }
        __builtin_amdgcn_s_setprio(0);
      }
      cur = cur + 1; if (cur >= 3) cur -= 3;
    }

    // fold: p = sum_ni x[row,col_ni] * Y; reduce over 16 cols; atomicAdd.
    // C layout (16x16): col = lane&15, row = (lane>>4)*4 + j.
#pragma unroll
    for (int mi = 0; mi < 4; ++mi)
#pragma unroll
      for (int j = 0; j < 4; ++j) {
        int row = m0 + wm * 64 + mi * 16 + (lane >> 4) * 4 + j;
        const size_t rb = (size_t)row * D_DIM + n0 + wn * 64 + l15;
        float p = 0.f;
#pragma unroll
        for (int ni = 0; ni < 4; ++ni) {
          float xv = bf16_f32(xh[rb + ni * 16]) + bf16_f32(xl[rb + ni * 16]);
          p += xv * acc[mi][ni][j];
        }
        p += __shfl_xor(p, 1, 64);
        p += __shfl_xor(p, 2, 64);
        p += __shfl_xor(p, 4, 64);
        p += __shfl_xor(p, 8, 64);
        if (l15 == 0) atomicAdd(&bias[row], p);
      }
  };

  if (half == 0) {
    phase(0, 0, 32);
    phase(1, 8, 16);
  } else {
    phase(1, 16, 32);
    phase(2, 16, 32);
    phase(3, 24, 32);
  }
}

// =====================================================================
// Q plain-bf16 GEMM with epilogue out[t,e] = S[t] * Q[t,e].
// R6 config: BM=BN=128, 4 waves (2x2), wave 64x64, 1024 blocks,
// LDS 32KB -> 4 blocks/CU, wait-then-barrier vmcnt(4).
// =====================================================================
__global__ __launch_bounds__(256, 4) void k_q_out(
    const unsigned short* __restrict__ xh,
    const unsigned short* __restrict__ qh_,
    const float* __restrict__ S, float* __restrict__ out) {
  __shared__ unsigned short sA[2][128 * 32];
  __shared__ unsigned short sB[2][128 * 32];
  const int tid = threadIdx.x;
  const int wave = tid >> 6, lane = tid & 63;
  const int wm = wave >> 1, wn = wave & 1;
  int sw0 = (blockIdx.x & 7) * 128 + (blockIdx.x >> 3);
  const int mb = sw0 >> 3, nb = sw0 & 7;
  const int m0 = mb * 128, n0 = nb * 128;
  const int hi32 = lane >> 5;
  const int l31 = lane & 31;

  const int srow0 = tid >> 2, srow1 = srow0 + 64;
  const int csrc0 = (tid & 3) ^ swz_row(srow0);
  const int csrc1 = (tid & 3) ^ swz_row(srow1);
  const size_t gaA0 = (size_t)(m0 + srow0) * D_DIM + csrc0 * 8;
  const size_t gaA1 = (size_t)(m0 + srow1) * D_DIM + csrc1 * 8;
  const size_t gaB0 = (size_t)(n0 + srow0) * D_DIM + csrc0 * 8;
  const size_t gaB1 = (size_t)(n0 + srow1) * D_DIM + csrc1 * 8;
  const int ldst0 = tid * 8, ldst1 = (tid + 256) * 8;

  f32x16 acc[2][2] = {};
  int aoff[2][2], boff[2][2];
#pragma unroll
  for (int mi = 0; mi < 2; ++mi) {
    int r = wm * 64 + mi * 32 + l31;
    int sw = swz_row(r);
#pragma unroll
    for (int kh = 0; kh < 2; ++kh)
      aoff[mi][kh] = r * 32 + (((kh * 2 + hi32) ^ sw) * 8);
  }
#pragma unroll
  for (int ni = 0; ni < 2; ++ni) {
    int r = wn * 64 + ni * 32 + l31;
    int sw = swz_row(r);
#pragma unroll
    for (int kh = 0; kh < 2; ++kh)
      boff[ni][kh] = r * 32 + (((kh * 2 + hi32) ^ sw) * 8);
  }

  auto stage = [&](int t, int buf) {
    const size_t ko = (size_t)t * 32;
    gload16(xh + gaA0 + ko, &sA[buf][ldst0]);
    gload16(xh + gaA1 + ko, &sA[buf][ldst1]);
    gload16(qh_ + gaB0 + ko, &sB[buf][ldst0]);
    gload16(qh_ + gaB1 + ko, &sB[buf][ldst1]);
  };

  stage(0, 0);
  stage(1, 1);
  for (int kt = 0; kt < 32; ++kt) {
    const int cur = kt & 1;
    if (kt < 31) { VMW(4); } else { VMW(0); }
    BAR;
#pragma unroll
    for (int kh = 0; kh < 2; ++kh) {
      bf16x8 fa[2], fb[2];
#pragma unroll
      for (int mi = 0; mi < 2; ++mi) fa[mi] = ldfrag(&sA[cur][aoff[mi][kh]]);
#pragma unroll
      for (int ni = 0; ni < 2; ++ni) fb[ni] = ldfrag(&sB[cur][boff[ni][kh]]);
      __builtin_amdgcn_s_setprio(1);
#pragma unroll
      for (int mi = 0; mi < 2; ++mi)
#pragma unroll
        for (int ni = 0; ni < 2; ++ni)
          acc[mi][ni] = __builtin_amdgcn_mfma_f32_32x32x16_bf16(fa[mi], fb[ni], acc[mi][ni], 0, 0, 0);
      __builtin_amdgcn_s_setprio(0);
    }
    BAR;
    if (kt + 2 <= 31) stage(kt + 2, cur);
  }

#pragma unroll
  for (int mi = 0; mi < 2; ++mi)
#pragma unroll
    for (int r = 0; r < 16; ++r) {
      int row = m0 + wm * 64 + mi * 32 + (r & 3) + 8 * (r >> 2) + 4 * hi32;
      float sc = S[row];
      float* orow = out + (size_t)row * D_DIM + n0 + wn * 64 + l31;
      orow[0] = sc * acc[mi][0][r];
      orow[32] = sc * acc[mi][1][r];
    }
}

// =====================================================================
extern "C" void kernel_launch(void* const* d_in, const int* in_sizes, int n_in,
                              void* d_out, int out_size, void* d_ws, size_t ws_size,
                              hipStream_t stream) {
  const float* x   = (const float*)d_in[0];
  const float* Wq  = (const float*)d_in[1];
  const float* Wk  = (const float*)d_in[2];
  const float* Wv  = (const float*)d_in[3];
  const float* Wih = (const float*)d_in[4];
  const float* Whh = (const float*)d_in[5];
  const float* bih = (const float*)d_in[6];
  float* out = (float*)d_out;

  char* ws = (char*)d_ws;
  size_t off = 0;
  auto alloc = [&](size_t bytes) -> char* {
    char* p = ws + off;
    off += (bytes + 255) & ~(size_t)255;
    return p;
  };
  unsigned short* xh   = (unsigned short*)alloc((size_t)M_TOK * D_DIM * 2);
  unsigned short* xl   = (unsigned short*)alloc((size_t)M_TOK * D_DIM * 2);
  unsigned short* wqh  = (unsigned short*)alloc((size_t)D_DIM * D_DIM * 2);
  unsigned short* wkth = (unsigned short*)alloc((size_t)D_DIM * D_DIM * 2);
  unsigned short* wktl = (unsigned short*)alloc((size_t)D_DIM * D_DIM * 2);
  unsigned short* wvth = (unsigned short*)alloc((size_t)D_DIM * D_DIM * 2);
  unsigned short* wvtl = (unsigned short*)alloc((size_t)D_DIM * D_DIM * 2);
  unsigned short* mph  = (unsigned short*)alloc((size_t)D_DIM * D_DIM * 2);
  unsigned short* mpl  = (unsigned short*)alloc((size_t)D_DIM * D_DIM * 2);
  float* Hf   = (float*)alloc((size_t)D_DIM * D_DIM * 4);
  float* bias = (float*)alloc((size_t)M_TOK * 4);
  float* Sbuf = (float*)alloc((size_t)M_TOK * 4);
  float* ubuf = (float*)alloc((size_t)T_DIM * 4);
  float* zbuf = (float*)alloc((size_t)T_DIM * 4);
  // Whh bf16 (8 MB) aliases wkth..wvtl (4 x 2 MB, dead after k_ht).
  unsigned short* whhb = wkth;
  (void)ws_size; (void)in_sizes; (void)n_in; (void)out_size;

  // 1. splits
  k_split<<<2048, 256, 0, stream>>>(x, M_TOK * D_DIM / 8, xh, xl);
  k_split_hi<<<512, 256, 0, stream>>>(Wq, D_DIM * D_DIM / 8, wqh);
  k_split_T<<<256, 256, 0, stream>>>(Wk, wkth, wktl);
  k_split_T<<<256, 256, 0, stream>>>(Wv, wvth, wvtl);

  // 2. zero bias accumulator and h0
  hipMemsetAsync(bias, 0, (size_t)M_TOK * 4, stream);
  hipMemsetAsync(zbuf, 0, (size_t)T_DIM * 4, stream);

  // 3. u vector
  k_u<<<T_DIM / 4, 256, 0, stream>>>(Wih, bih, ubuf);

  // 4. H[d'][d] = sum_e Wv[e,d'] Wk[e,d]  (fp32)
  k_ht<<<256, 256, 0, stream>>>(wvth, wvtl, wkth, wktl, Hf);

  // 5. M' = triangular-weighted symmetrization of H, hi/lo split
  k_nprime<<<256, 256, 0, stream>>>(Hf, mph, mpl);

  // 6. Whh -> bf16 (after k_ht: aliases the transposed weight splits)
  k_split_hi<<<1024, 256, 0, stream>>>(Whh, T_DIM * T_DIM / 8, whhb);

  // 7. Y = x.M' fused into bias (R1 geometry: 48 MFMA/wave/kt, BN=256)
  k_y_bias<<<256, 512, 0, stream>>>(xh, xl, mph, mpl, bias);

  // 8. 8-step tanh recurrence over batch rows (wave per row)
  for (int b = 0; b < B_DIM; ++b) {
    const float* hp = (b == 0) ? zbuf : (Sbuf + (size_t)(b - 1) * T_DIM);
    k_step_bf<<<T_DIM / 4, 256, 0, stream>>>(whhb, hp, ubuf, bias + (size_t)b * T_DIM,
                                             Sbuf + (size_t)b * T_DIM);
  }

  // 9. Q GEMM + scale-by-S epilogue
  k_q_out<<<1024, 256, 0, stream>>>(xh, wqh, Sbuf, out);
}

// Round 13
// 238.601 us; speedup vs baseline: 1.2169x; 1.0249x over previous
//
#include <hip/hip_runtime.h>
#include <stdint.h>

#define T_DIM 2048
#define D_DIM 1024
#define B_DIM 8
#define M_TOK (B_DIM * T_DIM)   // 16384 tokens
#define GAMMA_C 0.96875f

typedef float f32x4 __attribute__((ext_vector_type(4)));
typedef float f32x16 __attribute__((ext_vector_type(16)));
typedef float fl4 __attribute__((ext_vector_type(4)));
typedef __bf16 bf16x8 __attribute__((ext_vector_type(8)));
typedef unsigned short us8 __attribute__((ext_vector_type(8)));
typedef unsigned short us4 __attribute__((ext_vector_type(4)));

// ---------- bf16 helpers ----------
__device__ __forceinline__ unsigned short f32_bf16_rne(float f) {
  uint32_t u = __builtin_bit_cast(uint32_t, f);
  return (unsigned short)((u + 0x7FFFu + ((u >> 16) & 1u)) >> 16);
}
__device__ __forceinline__ float bf16_f32(unsigned short h) {
  uint32_t u = ((uint32_t)h) << 16;
  return __builtin_bit_cast(float, u);
}

// chunk swizzle: spreads fragment column-slice reads across bank groups
__device__ __forceinline__ int swz_row(int r) {
  return ((r >> 1) & 3) ^ ((r >> 3) & 3);
}

// ---------- global->LDS direct ----------
__device__ __forceinline__ void gload16(const void* g, void* l) {
  __builtin_amdgcn_global_load_lds(
      reinterpret_cast<const __attribute__((address_space(1))) uint32_t*>(
          reinterpret_cast<uintptr_t>(g)),
      reinterpret_cast<__attribute__((address_space(3))) uint32_t*>(
          reinterpret_cast<uintptr_t>(l)),
      16, 0, 0);
}

__device__ __forceinline__ bf16x8 ldfrag(const unsigned short* p) {
  us8 u = *reinterpret_cast<const us8*>(p);
  return __builtin_bit_cast(bf16x8, u);
}

#define VMW(n) asm volatile("s_waitcnt vmcnt(" #n ")" ::: "memory")
#define BAR    __builtin_amdgcn_s_barrier()

// ---------- split f32 -> (hi, lo) bf16, 16B stores ----------
__global__ __launch_bounds__(256) void k_split(const float* __restrict__ in, int n8,
                                               unsigned short* __restrict__ hi,
                                               unsigned short* __restrict__ lo) {
  int stride = gridDim.x * blockDim.x;
  for (int i = blockIdx.x * blockDim.x + threadIdx.x; i < n8; i += stride) {
    fl4 v0 = ((const fl4*)in)[i * 2];
    fl4 v1 = ((const fl4*)in)[i * 2 + 1];
    us8 h, l;
#pragma unroll
    for (int j = 0; j < 4; ++j) {
      unsigned short hb = f32_bf16_rne(v0[j]);
      h[j] = hb;
      l[j] = f32_bf16_rne(v0[j] - bf16_f32(hb));
      unsigned short hb1 = f32_bf16_rne(v1[j]);
      h[j + 4] = hb1;
      l[j + 4] = f32_bf16_rne(v1[j] - bf16_f32(hb1));
    }
    ((us8*)hi)[i] = h;
    ((us8*)lo)[i] = l;
  }
}

__global__ __launch_bounds__(256) void k_split_hi(const float* __restrict__ in, int n8,
                                                  unsigned short* __restrict__ hi) {
  int stride = gridDim.x * blockDim.x;
  for (int i = blockIdx.x * blockDim.x + threadIdx.x; i < n8; i += stride) {
    fl4 v0 = ((const fl4*)in)[i * 2];
    fl4 v1 = ((const fl4*)in)[i * 2 + 1];
    us8 h;
#pragma unroll
    for (int j = 0; j < 4; ++j) {
      h[j] = f32_bf16_rne(v0[j]);
      h[j + 4] = f32_bf16_rne(v1[j]);
    }
    ((us8*)hi)[i] = h;
  }
}

// ---------- transpose-split: out_t[d][e] = split(in[e][d]), 64x64 tiles ----------
__global__ __launch_bounds__(256) void k_split_T(const float* __restrict__ in,
                                                 unsigned short* __restrict__ th,
                                                 unsigned short* __restrict__ tl) {
  __shared__ float tile[64][69];
  int be = blockIdx.x >> 4, bd = blockIdx.x & 15;
  int e0 = be * 64, d0 = bd * 64;
  int r = threadIdx.x >> 4;
  int c = (threadIdx.x & 15) * 4;
#pragma unroll
  for (int it = 0; it < 4; ++it) {
    int rr = r + it * 16;
    fl4 v = *(const fl4*)(in + (size_t)(e0 + rr) * D_DIM + d0 + c);
#pragma unroll
    for (int j = 0; j < 4; ++j) tile[rr][c + j] = v[j];
  }
  __syncthreads();
#pragma unroll
  for (int it = 0; it < 4; ++it) {
    int dr = r + it * 16;
    us4 h, l;
#pragma unroll
    for (int j = 0; j < 4; ++j) {
      float f = tile[c + j][dr];
      h[j] = f32_bf16_rne(f);
      l[j] = f32_bf16_rne(f - bf16_f32(h[j]));
    }
    *(us4*)(th + (size_t)(d0 + dr) * D_DIM + e0 + c) = h;
    *(us4*)(tl + (size_t)(d0 + dr) * D_DIM + e0 + c) = l;
  }
}

// ---------- u[t] = GAMMA * rowsum(W_ih[t,:]) + b_ih[t] ----------
__global__ __launch_bounds__(256) void k_u(const float* __restrict__ Wih,
                                           const float* __restrict__ bih,
                                           float* __restrict__ u) {
  int wave = threadIdx.x >> 6, lane = threadIdx.x & 63;
  int t = blockIdx.x * 4 + wave;
  const fl4* row = (const fl4*)(Wih + (size_t)t * T_DIM);
  float s = 0.f;
#pragma unroll
  for (int i = 0; i < 8; ++i) {
    fl4 v = row[lane + i * 64];
    s += v[0] + v[1] + v[2] + v[3];
  }
#pragma unroll
  for (int m = 32; m >= 1; m >>= 1) s += __shfl_xor(s, m, 64);
  if (lane == 0) u[t] = GAMMA_C * s + bih[t];
}

// ---------- h_out[t] = tanh(u[t] + dot(Whh_bf16[t,:], h_prev) + bias_row[t]) ----------
__global__ __launch_bounds__(256) void k_step_bf(const unsigned short* __restrict__ Whh_b,
                                                 const float* __restrict__ hprev,
                                                 const float* __restrict__ u,
                                                 const float* __restrict__ biasrow,
                                                 float* __restrict__ hout) {
  int wave = threadIdx.x >> 6, lane = threadIdx.x & 63;
  int t = blockIdx.x * 4 + wave;
  const unsigned short* row = Whh_b + (size_t)t * T_DIM;
  float s = 0.f;
#pragma unroll
  for (int i = 0; i < 4; ++i) {
    us8 w = *(const us8*)(row + i * 512 + lane * 8);
    fl4 h0 = *(const fl4*)(hprev + i * 512 + lane * 8);
    fl4 h1 = *(const fl4*)(hprev + i * 512 + lane * 8 + 4);
    s += bf16_f32(w[0]) * h0[0] + bf16_f32(w[1]) * h0[1] +
         bf16_f32(w[2]) * h0[2] + bf16_f32(w[3]) * h0[3] +
         bf16_f32(w[4]) * h1[0] + bf16_f32(w[5]) * h1[1] +
         bf16_f32(w[6]) * h1[2] + bf16_f32(w[7]) * h1[3];
  }
#pragma unroll
  for (int m = 32; m >= 1; m >>= 1) s += __shfl_xor(s, m, 64);
  if (lane == 0) hout[t] = tanhf(u[t] + s + biasrow[t]);
}

// =====================================================================
// H[d'][d] = sum_e Wv[e,d'] * Wk[e,d], 3-term split, fp32 output.
// =====================================================================
__global__ __launch_bounds__(256) void k_ht(
    const unsigned short* __restrict__ ah, const unsigned short* __restrict__ al,
    const unsigned short* __restrict__ bh, const unsigned short* __restrict__ bl,
    float* __restrict__ Hf) {
  __shared__ unsigned short sAh[2][64 * 32], sAl[2][64 * 32];
  __shared__ unsigned short sBh[2][64 * 32], sBl[2][64 * 32];
  const int tid = threadIdx.x;
  const int wave = tid >> 6, lane = tid & 63;
  const int wm = wave >> 1, wn = wave & 1;
  const int m0 = (blockIdx.x >> 4) * 64, n0 = (blockIdx.x & 15) * 64;
  const int hi32 = lane >> 5;

  const int srow = tid >> 2;
  const int csrc = (tid & 3) ^ swz_row(srow);
  const size_t ga = (size_t)(m0 + srow) * D_DIM + csrc * 8;
  const size_t gb = (size_t)(n0 + srow) * D_DIM + csrc * 8;
  const int ldst = tid * 8;

  f32x16 acc = {};
  const int l31 = lane & 31;
  const int sw = swz_row(l31);
  const int ar = wm * 32 + l31;
  const int br = wn * 32 + l31;
  int aoff[2], boff[2];
#pragma unroll
  for (int kh = 0; kh < 2; ++kh) {
    aoff[kh] = ar * 32 + (((kh * 2 + hi32) ^ sw) * 8);
    boff[kh] = br * 32 + (((kh * 2 + hi32) ^ sw) * 8);
  }

  auto stage = [&](int t, int buf) {
    const size_t ko = (size_t)t * 32;
    gload16(ah + ga + ko, &sAh[buf][ldst]);
    gload16(al + ga + ko, &sAl[buf][ldst]);
    gload16(bh + gb + ko, &sBh[buf][ldst]);
    gload16(bl + gb + ko, &sBl[buf][ldst]);
  };

  stage(0, 0);
  stage(1, 1);
  for (int kt = 0; kt < 32; ++kt) {
    const int cur = kt & 1;
    if (kt < 31) { VMW(4); } else { VMW(0); }
    BAR;
#pragma unroll
    for (int kh = 0; kh < 2; ++kh) {
      bf16x8 fah = ldfrag(&sAh[cur][aoff[kh]]);
      bf16x8 fal = ldfrag(&sAl[cur][aoff[kh]]);
      bf16x8 fbh = ldfrag(&sBh[cur][boff[kh]]);
      bf16x8 fbl = ldfrag(&sBl[cur][boff[kh]]);
      acc = __builtin_amdgcn_mfma_f32_32x32x16_bf16(fah, fbh, acc, 0, 0, 0);
      acc = __builtin_amdgcn_mfma_f32_32x32x16_bf16(fah, fbl, acc, 0, 0, 0);
      acc = __builtin_amdgcn_mfma_f32_32x32x16_bf16(fal, fbh, acc, 0, 0, 0);
    }
    BAR;
    if (kt + 2 <= 31) stage(kt + 2, cur);
  }
#pragma unroll
  for (int r = 0; r < 16; ++r) {
    int row = m0 + wm * 32 + (r & 3) + 8 * (r >> 2) + 4 * hi32;
    int col = n0 + wn * 32 + l31;
    Hf[(size_t)row * D_DIM + col] = acc[r];
  }
}

// =====================================================================
// M'[d'][d] = H[d',d]+H[d,d'] (d>d'); H[d,d] (d==d'); 0 (d<d').
// =====================================================================
__global__ __launch_bounds__(256) void k_nprime(const float* __restrict__ Hf,
                                                unsigned short* __restrict__ mh,
                                                unsigned short* __restrict__ ml) {
  __shared__ float t2[64][65];
  const int ti = blockIdx.x >> 4;
  const int tj = blockIdx.x & 15;
  const int r0 = ti * 64, c0 = tj * 64;
  const int a = threadIdx.x >> 2;
  const int b4 = (threadIdx.x & 3) * 16;
  if (tj < ti) {
#pragma unroll
    for (int j = 0; j < 16; ++j) {
      size_t ad = (size_t)(r0 + a) * D_DIM + c0 + b4 + j;
      mh[ad] = 0;
      ml[ad] = 0;
    }
    return;
  }
#pragma unroll
  for (int j = 0; j < 16; j += 4) {
    fl4 v = *(const fl4*)(Hf + (size_t)(c0 + a) * D_DIM + r0 + b4 + j);
#pragma unroll
    for (int q = 0; q < 4; ++q) t2[a][b4 + j + q] = v[q];
  }
  __syncthreads();
#pragma unroll
  for (int j = 0; j < 16; ++j) {
    int dp = r0 + a;
    int dd = c0 + b4 + j;
    float v = 0.f;
    if (dd > dp)       v = Hf[(size_t)dp * D_DIM + dd] + t2[b4 + j][a];
    else if (dd == dp) v = Hf[(size_t)dp * D_DIM + dd];
    unsigned short hb = f32_bf16_rne(v);
    unsigned short lb = f32_bf16_rne(v - bf16_f32(hb));
    size_t ad = (size_t)dp * D_DIM + dd;
    mh[ad] = hb;
    ml[ad] = lb;
  }
}

// =====================================================================
// Y = x.M'^T fused bias — R12 structure with the spill killed:
//   (1) __launch_bounds__(512, 1): VGPR cap 256 (LDS 144KB already forces
//       1 block/CU, so the old (512,2)'s 128-cap bought nothing and cost
//       a ~1-reg/kt scratch spill: R12 WRITE_SIZE 33.5 MB, VGPR pinned 128).
//   (2) B-frags loaded/consumed in 2 ni-pairs: peak live frags
//       A(32 VGPR) + B(16) instead of 64.
//   Geometry: 512 thr / 8 waves (2m x 4n), wave 64x64 in 16x16x32 frags,
//   48 MFMA/wave/kt; BM=128, BN=256, BK=32; 3-buf one-barrier rotation;
//   triangular K-split, 256 blocks x exactly 40 kt.
// =====================================================================
__global__ __launch_bounds__(512, 1) void k_y_bias(
    const unsigned short* __restrict__ xh, const unsigned short* __restrict__ xl,
    const unsigned short* __restrict__ bh, const unsigned short* __restrict__ bl,
    float* __restrict__ bias) {
  __shared__ unsigned short sAh[3][128 * 32], sAl[3][128 * 32];
  __shared__ unsigned short sBh[3][256 * 32], sBl[3][256 * 32];
  const int tid = threadIdx.x;
  const int wave = tid >> 6, lane = tid & 63;
  const int wm = wave >> 2;      // 0..1
  const int wn = wave & 3;       // 0..3
  const int xcd = blockIdx.x & 7, seq = blockIdx.x >> 3;
  const int mb = xcd * 16 + (seq >> 1);
  const int half = seq & 1;
  const int m0 = mb * 128;
  const int l15 = lane & 15;
  const int kc = lane >> 4;      // k-chunk 0..3 for 16x16x32 A/B frags

  const int srow = tid >> 2;
  const int csrc = (tid & 3) ^ swz_row(srow);
  const size_t gA = (size_t)(m0 + srow) * D_DIM + csrc * 8;
  const int ldstA = tid * 8;
  const int ldstB0 = tid * 8, ldstB1 = (tid + 512) * 8;

  int aoff[4], boff[4];
#pragma unroll
  for (int mi = 0; mi < 4; ++mi) {
    int r = wm * 64 + mi * 16 + l15;
    aoff[mi] = r * 32 + ((kc ^ swz_row(r)) * 8);
  }
#pragma unroll
  for (int ni = 0; ni < 4; ++ni) {
    int r = wn * 64 + ni * 16 + l15;
    boff[ni] = r * 32 + ((kc ^ swz_row(r)) * 8);
  }

  auto phase = [&](int nb, int k0, int ke) {
    const int n0 = nb * 256;
    const size_t gB0 = (size_t)(n0 + srow) * D_DIM + csrc * 8;
    const size_t gB1 = (size_t)(n0 + srow + 128) * D_DIM + csrc * 8;

    auto stage = [&](int t, int buf) {
      const size_t ko = (size_t)t * 32;
      gload16(xh + gA + ko, &sAh[buf][ldstA]);
      gload16(xl + gA + ko, &sAl[buf][ldstA]);
      gload16(bh + gB0 + ko, &sBh[buf][ldstB0]);
      gload16(bh + gB1 + ko, &sBh[buf][ldstB1]);
      gload16(bl + gB0 + ko, &sBl[buf][ldstB0]);
      gload16(bl + gB1 + ko, &sBl[buf][ldstB1]);
    };

    f32x4 acc[4][4] = {};
    BAR;                          // fence prev phase's reads vs restage
    stage(k0, 0);
    stage(k0 + 1, 1);
    int cur = 0;
    for (int kt = k0; kt < ke; ++kt) {
      if (kt < ke - 1) { VMW(6); } else { VMW(0); }
      BAR;
      int nx = cur + 2; if (nx >= 3) nx -= 3;
      if (kt + 2 < ke) stage(kt + 2, nx);
      {
        bf16x8 fah[4], fal[4];
#pragma unroll
        for (int mi = 0; mi < 4; ++mi) {
          fah[mi] = ldfrag(&sAh[cur][aoff[mi]]);
          fal[mi] = ldfrag(&sAl[cur][aoff[mi]]);
        }
#pragma unroll
        for (int nh = 0; nh < 2; ++nh) {   // 2 B-pairs: halves live-frag set
          bf16x8 fbh_[2], fbl_[2];
#pragma unroll
          for (int nj = 0; nj < 2; ++nj) {
            fbh_[nj] = ldfrag(&sBh[cur][boff[nh * 2 + nj]]);
            fbl_[nj] = ldfrag(&sBl[cur][boff[nh * 2 + nj]]);
          }
          __builtin_amdgcn_s_setprio(1);
#pragma unroll
          for (int mi = 0; mi < 4; ++mi)
#pragma unroll
            for (int nj = 0; nj < 2; ++nj) {
              const int ni = nh * 2 + nj;
              acc[mi][ni] = __builtin_amdgcn_mfma_f32_16x16x32_bf16(fah[mi], fbh_[nj], acc[mi][ni], 0, 0, 0);
              acc[mi][ni] = __builtin_amdgcn_mfma_f32_16x16x32_bf16(fah[mi], fbl_[nj], acc[mi][ni], 0, 0, 0);
              acc[mi][ni] = __builtin_amdgcn_mfma_f32_16x16x32_bf16(fal[mi], fbh_[nj], acc[mi][ni], 0, 0, 0);
            }
          __builtin_amdgcn_s_setprio(0);
        }
      }
      cur = cur + 1; if (cur >= 3) cur -= 3;
    }

    // fold: p = sum_ni x[row,col_ni] * Y; reduce over 16 cols; atomicAdd.
#pragma unroll
    for (int mi = 0; mi < 4; ++mi)
#pragma unroll
      for (int j = 0; j < 4; ++j) {
        int row = m0 + wm * 64 + mi * 16 + (lane >> 4) * 4 + j;
        const size_t rb = (size_t)row * D_DIM + n0 + wn * 64 + l15;
        float p = 0.f;
#pragma unroll
        for (int ni = 0; ni < 4; ++ni) {
          float xv = bf16_f32(xh[rb + ni * 16]) + bf16_f32(xl[rb + ni * 16]);
          p += xv * acc[mi][ni][j];
        }
        p += __shfl_xor(p, 1, 64);
        p += __shfl_xor(p, 2, 64);
        p += __shfl_xor(p, 4, 64);
        p += __shfl_xor(p, 8, 64);
        if (l15 == 0) atomicAdd(&bias[row], p);
      }
  };

  if (half == 0) {
    phase(0, 0, 32);
    phase(1, 8, 16);
  } else {
    phase(1, 16, 32);
    phase(2, 16, 32);
    phase(3, 24, 32);
  }
}

// =====================================================================
// Q plain-bf16 GEMM with epilogue out[t,e] = S[t] * Q[t,e].
// R6 config: BM=BN=128, 4 waves (2x2), wave 64x64, 1024 blocks,
// LDS 32KB -> 4 blocks/CU, wait-then-barrier vmcnt(4).
// =====================================================================
__global__ __launch_bounds__(256, 4) void k_q_out(
    const unsigned short* __restrict__ xh,
    const unsigned short* __restrict__ qh_,
    const float* __restrict__ S, float* __restrict__ out) {
  __shared__ unsigned short sA[2][128 * 32];
  __shared__ unsigned short sB[2][128 * 32];
  const int tid = threadIdx.x;
  const int wave = tid >> 6, lane = tid & 63;
  const int wm = wave >> 1, wn = wave & 1;
  int sw0 = (blockIdx.x & 7) * 128 + (blockIdx.x >> 3);
  const int mb = sw0 >> 3, nb = sw0 & 7;
  const int m0 = mb * 128, n0 = nb * 128;
  const int hi32 = lane >> 5;
  const int l31 = lane & 31;

  const int srow0 = tid >> 2, srow1 = srow0 + 64;
  const int csrc0 = (tid & 3) ^ swz_row(srow0);
  const int csrc1 = (tid & 3) ^ swz_row(srow1);
  const size_t gaA0 = (size_t)(m0 + srow0) * D_DIM + csrc0 * 8;
  const size_t gaA1 = (size_t)(m0 + srow1) * D_DIM + csrc1 * 8;
  const size_t gaB0 = (size_t)(n0 + srow0) * D_DIM + csrc0 * 8;
  const size_t gaB1 = (size_t)(n0 + srow1) * D_DIM + csrc1 * 8;
  const int ldst0 = tid * 8, ldst1 = (tid + 256) * 8;

  f32x16 acc[2][2] = {};
  int aoff[2][2], boff[2][2];
#pragma unroll
  for (int mi = 0; mi < 2; ++mi) {
    int r = wm * 64 + mi * 32 + l31;
    int sw = swz_row(r);
#pragma unroll
    for (int kh = 0; kh < 2; ++kh)
      aoff[mi][kh] = r * 32 + (((kh * 2 + hi32) ^ sw) * 8);
  }
#pragma unroll
  for (int ni = 0; ni < 2; ++ni) {
    int r = wn * 64 + ni * 32 + l31;
    int sw = swz_row(r);
#pragma unroll
    for (int kh = 0; kh < 2; ++kh)
      boff[ni][kh] = r * 32 + (((kh * 2 + hi32) ^ sw) * 8);
  }

  auto stage = [&](int t, int buf) {
    const size_t ko = (size_t)t * 32;
    gload16(xh + gaA0 + ko, &sA[buf][ldst0]);
    gload16(xh + gaA1 + ko, &sA[buf][ldst1]);
    gload16(qh_ + gaB0 + ko, &sB[buf][ldst0]);
    gload16(qh_ + gaB1 + ko, &sB[buf][ldst1]);
  };

  stage(0, 0);
  stage(1, 1);
  for (int kt = 0; kt < 32; ++kt) {
    const int cur = kt & 1;
    if (kt < 31) { VMW(4); } else { VMW(0); }
    BAR;
#pragma unroll
    for (int kh = 0; kh < 2; ++kh) {
      bf16x8 fa[2], fb[2];
#pragma unroll
      for (int mi = 0; mi < 2; ++mi) fa[mi] = ldfrag(&sA[cur][aoff[mi][kh]]);
#pragma unroll
      for (int ni = 0; ni < 2; ++ni) fb[ni] = ldfrag(&sB[cur][boff[ni][kh]]);
      __builtin_amdgcn_s_setprio(1);
#pragma unroll
      for (int mi = 0; mi < 2; ++mi)
#pragma unroll
        for (int ni = 0; ni < 2; ++ni)
          acc[mi][ni] = __builtin_amdgcn_mfma_f32_32x32x16_bf16(fa[mi], fb[ni], acc[mi][ni], 0, 0, 0);
      __builtin_amdgcn_s_setprio(0);
    }
    BAR;
    if (kt + 2 <= 31) stage(kt + 2, cur);
  }

#pragma unroll
  for (int mi = 0; mi < 2; ++mi)
#pragma unroll
    for (int r = 0; r < 16; ++r) {
      int row = m0 + wm * 64 + mi * 32 + (r & 3) + 8 * (r >> 2) + 4 * hi32;
      float sc = S[row];
      float* orow = out + (size_t)row * D_DIM + n0 + wn * 64 + l31;
      orow[0] = sc * acc[mi][0][r];
      orow[32] = sc * acc[mi][1][r];
    }
}

// =====================================================================
extern "C" void kernel_launch(void* const* d_in, const int* in_sizes, int n_in,
                              void* d_out, int out_size, void* d_ws, size_t ws_size,
                              hipStream_t stream) {
  const float* x   = (const float*)d_in[0];
  const float* Wq  = (const float*)d_in[1];
  const float* Wk  = (const float*)d_in[2];
  const float* Wv  = (const float*)d_in[3];
  const float* Wih = (const float*)d_in[4];
  const float* Whh = (const float*)d_in[5];
  const float* bih = (const float*)d_in[6];
  float* out = (float*)d_out;

  char* ws = (char*)d_ws;
  size_t off = 0;
  auto alloc = [&](size_t bytes) -> char* {
    char* p = ws + off;
    off += (bytes + 255) & ~(size_t)255;
    return p;
  };
  unsigned short* xh   = (unsigned short*)alloc((size_t)M_TOK * D_DIM * 2);
  unsigned short* xl   = (unsigned short*)alloc((size_t)M_TOK * D_DIM * 2);
  unsigned short* wqh  = (unsigned short*)alloc((size_t)D_DIM * D_DIM * 2);
  unsigned short* wkth = (unsigned short*)alloc((size_t)D_DIM * D_DIM * 2);
  unsigned short* wktl = (unsigned short*)alloc((size_t)D_DIM * D_DIM * 2);
  unsigned short* wvth = (unsigned short*)alloc((size_t)D_DIM * D_DIM * 2);
  unsigned short* wvtl = (unsigned short*)alloc((size_t)D_DIM * D_DIM * 2);
  unsigned short* mph  = (unsigned short*)alloc((size_t)D_DIM * D_DIM * 2);
  unsigned short* mpl  = (unsigned short*)alloc((size_t)D_DIM * D_DIM * 2);
  float* Hf   = (float*)alloc((size_t)D_DIM * D_DIM * 4);
  float* bias = (float*)alloc((size_t)M_TOK * 4);
  float* Sbuf = (float*)alloc((size_t)M_TOK * 4);
  float* ubuf = (float*)alloc((size_t)T_DIM * 4);
  float* zbuf = (float*)alloc((size_t)T_DIM * 4);
  // Whh bf16 (8 MB) aliases wkth..wvtl (4 x 2 MB, dead after k_ht).
  unsigned short* whhb = wkth;
  (void)ws_size; (void)in_sizes; (void)n_in; (void)out_size;

  // 1. splits
  k_split<<<2048, 256, 0, stream>>>(x, M_TOK * D_DIM / 8, xh, xl);
  k_split_hi<<<512, 256, 0, stream>>>(Wq, D_DIM * D_DIM / 8, wqh);
  k_split_T<<<256, 256, 0, stream>>>(Wk, wkth, wktl);
  k_split_T<<<256, 256, 0, stream>>>(Wv, wvth, wvtl);

  // 2. zero bias accumulator and h0
  hipMemsetAsync(bias, 0, (size_t)M_TOK * 4, stream);
  hipMemsetAsync(zbuf, 0, (size_t)T_DIM * 4, stream);

  // 3. u vector
  k_u<<<T_DIM / 4, 256, 0, stream>>>(Wih, bih, ubuf);

  // 4. H[d'][d] = sum_e Wv[e,d'] Wk[e,d]  (fp32)
  k_ht<<<256, 256, 0, stream>>>(wvth, wvtl, wkth, wktl, Hf);

  // 5. M' = triangular-weighted symmetrization of H, hi/lo split
  k_nprime<<<256, 256, 0, stream>>>(Hf, mph, mpl);

  // 6. Whh -> bf16 (after k_ht: aliases the transposed weight splits)
  k_split_hi<<<1024, 256, 0, stream>>>(Whh, T_DIM * T_DIM / 8, whhb);

  // 7. Y = x.M' fused into bias (R12 geometry, spill-free)
  k_y_bias<<<256, 512, 0, stream>>>(xh, xl, mph, mpl, bias);

  // 8. 8-step tanh recurrence over batch rows (wave per row)
  for (int b = 0; b < B_DIM; ++b) {
    const float* hp = (b == 0) ? zbuf : (Sbuf + (size_t)(b - 1) * T_DIM);
    k_step_bf<<<T_DIM / 4, 256, 0, stream>>>(whhb, hp, ubuf, bias + (size_t)b * T_DIM,
                                             Sbuf + (size_t)b * T_DIM);
  }

  // 9. Q GEMM + scale-by-S epilogue
  k_q_out<<<1024, 256, 0, stream>>>(xh, wqh, Sbuf, out);
}